// Round 1
// baseline (221.177 us; speedup 1.0000x reference)
//
#include <hip/hip_runtime.h>
#include <hip/hip_bf16.h>

#define NPIX   784
#define CIN    384
#define NHEADS 12
#define HDIM   32
#define MID    384
#define QKV_M  1152
#define SCALE  0.17677669529663687f
#define W1SZ   442368   // 1152*384
#define W2SZ   147456   // 384*384

typedef __attribute__((ext_vector_type(8))) short bf16x8;
typedef __attribute__((ext_vector_type(4))) float f32x4;
typedef __attribute__((ext_vector_type(4))) unsigned short ush4;
typedef unsigned short u16;
typedef unsigned int u32;

__device__ __forceinline__ u16 f2bf(float f) {
  union { float f; u32 u; } v; v.f = f;
  u32 u = v.u;
  u += 0x7fffu + ((u >> 16) & 1u);
  return (u16)(u >> 16);
}
__device__ __forceinline__ float bf2f(u16 h) {
  union { u32 u; float f; } v; v.u = ((u32)h) << 16;
  return v.f;
}

#define GLL16(gsrc, ldst) \
  __builtin_amdgcn_global_load_lds((const __attribute__((address_space(1))) void*)(gsrc), \
                                   (__attribute__((address_space(3))) void*)(ldst), 16, 0, 0)

// ---------------- prepass: weights -> bf16 (SCALE folded into q, gamma into proj) ----
__global__ __launch_bounds__(256) void prep_weights(
    const float* __restrict__ Wq, const float* __restrict__ bq,
    const float* __restrict__ Wkv, const float* __restrict__ bkv,
    const float* __restrict__ Wproj, const float* __restrict__ bproj,
    const float* __restrict__ gamma,
    u16* __restrict__ wqkv, u16* __restrict__ wp_hi, u16* __restrict__ wp_lo,
    float* __restrict__ bqkv, float* __restrict__ bp)
{
  const int total = W1SZ + W2SZ + QKV_M + MID;
  for (int i = blockIdx.x * blockDim.x + threadIdx.x; i < total; i += gridDim.x * blockDim.x) {
    if (i < W1SZ) {
      const int m = i / CIN;
      const float v = (m < MID) ? Wq[i] * SCALE : Wkv[i - W2SZ];
      wqkv[i] = f2bf(v);
    } else if (i < W1SZ + W2SZ) {
      const int j = i - W1SZ;
      const int o = j / MID;
      const float v = Wproj[j] * gamma[o];
      const u16 hb = f2bf(v);
      wp_hi[j] = hb;
      wp_lo[j] = f2bf(v - bf2f(hb));
    } else if (i < W1SZ + W2SZ + QKV_M) {
      const int m = i - W1SZ - W2SZ;
      bqkv[m] = (m < MID) ? bq[m] * SCALE : bkv[m - MID];
    } else {
      const int o = i - W1SZ - W2SZ - QKV_M;
      bp[o] = bproj[o] * gamma[o];
    }
  }
}

// ---------------- prepass: x [B][C][N] f32 -> xT [B][N][C] bf16 ----------------------
__global__ __launch_bounds__(256) void prep_x(const float* __restrict__ x, u16* __restrict__ xT) {
  __shared__ float tile[32][33];
  const int b = blockIdx.z, c0 = blockIdx.y * 32, n0 = blockIdx.x * 32;
  const int tx = threadIdx.x, ty = threadIdx.y;
  #pragma unroll
  for (int j = 0; j < 4; ++j) {
    const int c = c0 + ty + j * 8, n = n0 + tx;
    tile[ty + j * 8][tx] = (n < NPIX) ? x[((size_t)b * CIN + c) * NPIX + n] : 0.f;
  }
  __syncthreads();
  #pragma unroll
  for (int j = 0; j < 4; ++j) {
    const int n = n0 + ty + j * 8, c = c0 + tx;
    if (n < NPIX) xT[((size_t)b * NPIX + n) * CIN + c] = f2bf(tile[tx][ty + j * 8]);
  }
}

// ---------------- QKV GEMM: [1152x384] @ [384x784] per batch ------------------------
// A = wqkv rows (bf16), B = xT rows ([n][k] layout). Outputs:
//   q_s [b][h][n][32] (scaled), k_s [b][h][n][32], vt [b][h][32][n]
__global__ __launch_bounds__(256) void qkv_gemm(
    const u16* __restrict__ wqkv, const float* __restrict__ bqkv,
    const u16* __restrict__ xT,
    u16* __restrict__ q_s, u16* __restrict__ k_s, u16* __restrict__ vt)
{
  __shared__ u16 As[128 * 32];   // 64B rows, XOR chunk swizzle key=(row>>1)&3
  __shared__ u16 Bs[64 * 32];
  const int b = blockIdx.z;
  const int m0 = blockIdx.x * 128;
  const int n0 = blockIdx.y * 64;
  const int tid = threadIdx.x, l = tid & 63, w = tid >> 6;
  const int wm = (w & 1) * 64, wn = (w >> 1) * 32;

  const f32x4 vzero = {0.f, 0.f, 0.f, 0.f};
  f32x4 acc[4][2];
  #pragma unroll
  for (int mi = 0; mi < 4; ++mi)
    #pragma unroll
    for (int ni = 0; ni < 2; ++ni) acc[mi][ni] = vzero;

  for (int kt = 0; kt < 12; ++kt) {
    __syncthreads();
    #pragma unroll
    for (int s = 0; s < 2; ++s) {   // stage A: 8KB, wave-chunked
      const int o = w * 2048 + s * 1024 + l * 16;
      const int row = o >> 6;
      const int c = ((o >> 4) & 3) ^ ((row >> 1) & 3);
      const u16* g = wqkv + (size_t)(m0 + row) * CIN + kt * 32 + c * 8;
      GLL16(g, (char*)As + w * 2048 + s * 1024);
    }
    {                               // stage B: 4KB
      const int o = w * 1024 + l * 16;
      const int row = o >> 6;
      const int c = ((o >> 4) & 3) ^ ((row >> 1) & 3);
      int nr = n0 + row; nr = nr > NPIX - 1 ? NPIX - 1 : nr;
      const u16* g = xT + ((size_t)b * NPIX + nr) * CIN + kt * 32 + c * 8;
      GLL16(g, (char*)Bs + w * 1024);
    }
    __syncthreads();
    bf16x8 af[4], bfr[2];
    #pragma unroll
    for (int mi = 0; mi < 4; ++mi) {
      const int row = wm + mi * 16 + (l & 15);
      const int byte = row * 64 + (((l >> 4) ^ ((row >> 1) & 3)) << 4);
      af[mi] = *(const bf16x8*)((const char*)As + byte);
    }
    #pragma unroll
    for (int ni = 0; ni < 2; ++ni) {
      const int row = wn + ni * 16 + (l & 15);
      const int byte = row * 64 + (((l >> 4) ^ ((row >> 1) & 3)) << 4);
      bfr[ni] = *(const bf16x8*)((const char*)Bs + byte);
    }
    #pragma unroll
    for (int mi = 0; mi < 4; ++mi)
      #pragma unroll
      for (int ni = 0; ni < 2; ++ni)
        acc[mi][ni] = __builtin_amdgcn_mfma_f32_16x16x32_bf16(af[mi], bfr[ni], acc[mi][ni], 0, 0, 0);
  }

  #pragma unroll
  for (int mi = 0; mi < 4; ++mi) {
    const int mrow0 = m0 + wm + mi * 16 + ((l >> 4) << 2);
    #pragma unroll
    for (int ni = 0; ni < 2; ++ni) {
      const int n = n0 + wn + ni * 16 + (l & 15);
      if (n >= NPIX) continue;
      const float v0 = acc[mi][ni][0] + bqkv[mrow0 + 0];
      const float v1 = acc[mi][ni][1] + bqkv[mrow0 + 1];
      const float v2 = acc[mi][ni][2] + bqkv[mrow0 + 2];
      const float v3 = acc[mi][ni][3] + bqkv[mrow0 + 3];
      if (mrow0 < MID) {
        const int h = mrow0 >> 5, d = mrow0 & 31;
        ush4 pk; pk[0] = f2bf(v0); pk[1] = f2bf(v1); pk[2] = f2bf(v2); pk[3] = f2bf(v3);
        *(ush4*)(q_s + (((size_t)b * NHEADS + h) * NPIX + n) * HDIM + d) = pk;
      } else if (mrow0 < 2 * MID) {
        const int m2 = mrow0 - MID, h = m2 >> 5, d = m2 & 31;
        ush4 pk; pk[0] = f2bf(v0); pk[1] = f2bf(v1); pk[2] = f2bf(v2); pk[3] = f2bf(v3);
        *(ush4*)(k_s + (((size_t)b * NHEADS + h) * NPIX + n) * HDIM + d) = pk;
      } else {
        const int m2 = mrow0 - 2 * MID, h = m2 >> 5, d = m2 & 31;
        u16* p = vt + (((size_t)b * NHEADS + h) * HDIM + d) * NPIX + n;
        p[0] = f2bf(v0); p[NPIX] = f2bf(v1); p[2 * NPIX] = f2bf(v2); p[3 * NPIX] = f2bf(v3);
      }
    }
  }
}

// ---------------- flash attention with inline rel-pos bias gather -------------------
__global__ __launch_bounds__(256) void attn(
    const u16* __restrict__ q_s, const u16* __restrict__ k_s, const u16* __restrict__ vt,
    const int* __restrict__ rel_index, const float* __restrict__ bias_table,
    float* __restrict__ oT)
{
  __shared__ u16 Ks[64 * 32];      // [kv][d], 64B rows, key=(row>>1)&3
  __shared__ u16 Vs[32 * 64];      // [d][kv], 128B rows, key=row&7
  __shared__ u16 Ps[4][16 * 64];   // per-wave P, 128B rows, key=row&7
  const int qt = blockIdx.x, h = blockIdx.y, b = blockIdx.z;
  const int bh = b * NHEADS + h;
  const int tid = threadIdx.x, l = tid & 63, w = tid >> 6;
  const int qbase = qt * 64 + w * 16;

  int qrow = qbase + (l & 15); qrow = qrow > NPIX - 1 ? NPIX - 1 : qrow;
  const bf16x8 qf = *(const bf16x8*)(q_s + ((size_t)bh * NPIX + qrow) * HDIM + ((l >> 4) << 3));

  const f32x4 vzero = {0.f, 0.f, 0.f, 0.f};
  f32x4 oacc[2]; oacc[0] = vzero; oacc[1] = vzero;
  float mrun[4], lrun[4];
  #pragma unroll
  for (int jr = 0; jr < 4; ++jr) { mrun[jr] = -1e30f; lrun[jr] = 0.f; }
  const int i4 = qbase + ((l >> 4) << 2);
  int icl[4];
  #pragma unroll
  for (int jr = 0; jr < 4; ++jr) { int i = i4 + jr; icl[jr] = i > NPIX - 1 ? NPIX - 1 : i; }

  for (int t = 0; t < 13; ++t) {
    const int kv0 = t * 64;
    __syncthreads();
    {   // stage K [64][32]
      const int o = w * 1024 + l * 16;
      const int row = o >> 6;
      const int c = ((o >> 4) & 3) ^ ((row >> 1) & 3);
      int rg = kv0 + row; rg = rg > NPIX - 1 ? NPIX - 1 : rg;
      const u16* g = k_s + ((size_t)bh * NPIX + rg) * HDIM + c * 8;
      GLL16(g, (char*)Ks + w * 1024);
    }
    {   // stage V [32][64]
      const int o = w * 1024 + l * 16;
      const int d = o >> 7;
      const int c = ((o >> 4) & 7) ^ (d & 7);
      int col = kv0 + c * 8; col = col > NPIX - 8 ? NPIX - 8 : col;
      const u16* g = vt + ((size_t)bh * HDIM + d) * NPIX + col;
      GLL16(g, (char*)Vs + w * 1024);
    }
    __syncthreads();

    f32x4 s[4];
    #pragma unroll
    for (int nf = 0; nf < 4; ++nf) {
      const int row = nf * 16 + (l & 15);
      const int byte = row * 64 + (((l >> 4) ^ ((row >> 1) & 3)) << 4);
      const bf16x8 kf = *(const bf16x8*)((const char*)Ks + byte);
      s[nf] = __builtin_amdgcn_mfma_f32_16x16x32_bf16(qf, kf, vzero, 0, 0, 0);
    }

    float pm[4], lg[4][4];
    #pragma unroll
    for (int jr = 0; jr < 4; ++jr) pm[jr] = -1e30f;
    #pragma unroll
    for (int nf = 0; nf < 4; ++nf) {
      const int j = kv0 + nf * 16 + (l & 15);
      const bool jv = j < NPIX;
      const int jc = jv ? j : NPIX - 1;
      #pragma unroll
      for (int jr = 0; jr < 4; ++jr) {
        const int ridx = rel_index[(size_t)icl[jr] * NPIX + jc];
        const float bias = bias_table[ridx * NHEADS + h];
        const float v = jv ? s[nf][jr] + bias : -1e30f;
        lg[nf][jr] = v;
        pm[jr] = fmaxf(pm[jr], v);
      }
    }
    #pragma unroll
    for (int off = 1; off < 16; off <<= 1)
      #pragma unroll
      for (int jr = 0; jr < 4; ++jr)
        pm[jr] = fmaxf(pm[jr], __shfl_xor(pm[jr], off, 64));

    float corr[4], rs[4];
    #pragma unroll
    for (int jr = 0; jr < 4; ++jr) {
      const float mnew = fmaxf(mrun[jr], pm[jr]);
      corr[jr] = __expf(mrun[jr] - mnew);
      mrun[jr] = mnew;
      rs[jr] = 0.f;
    }
    #pragma unroll
    for (int nf = 0; nf < 4; ++nf) {
      #pragma unroll
      for (int jr = 0; jr < 4; ++jr) {
        const float p = __expf(lg[nf][jr] - mrun[jr]);
        rs[jr] += p;
        const int r = ((l >> 4) << 2) + jr;
        const int j = nf * 16 + (l & 15);
        const int byte = r * 128 + ((((j >> 3)) ^ (r & 7)) << 4) + (j & 7) * 2;
        *(u16*)((char*)Ps[w] + byte) = f2bf(p);
      }
    }
    #pragma unroll
    for (int off = 1; off < 16; off <<= 1)
      #pragma unroll
      for (int jr = 0; jr < 4; ++jr)
        rs[jr] += __shfl_xor(rs[jr], off, 64);
    #pragma unroll
    for (int jr = 0; jr < 4; ++jr) lrun[jr] = lrun[jr] * corr[jr] + rs[jr];
    #pragma unroll
    for (int nf2 = 0; nf2 < 2; ++nf2)
      #pragma unroll
      for (int jr = 0; jr < 4; ++jr) oacc[nf2][jr] *= corr[jr];

    #pragma unroll
    for (int kk = 0; kk < 2; ++kk) {   // PV
      const int pr = l & 15;
      const int pc = kk * 4 + (l >> 4);
      const int pbyte = pr * 128 + ((pc ^ (pr & 7)) << 4);
      const bf16x8 pa = *(const bf16x8*)((const char*)Ps[w] + pbyte);
      #pragma unroll
      for (int nf2 = 0; nf2 < 2; ++nf2) {
        const int d = nf2 * 16 + (l & 15);
        const int vbyte = d * 128 + ((pc ^ (d & 7)) << 4);
        const bf16x8 vb = *(const bf16x8*)((const char*)Vs + vbyte);
        oacc[nf2] = __builtin_amdgcn_mfma_f32_16x16x32_bf16(pa, vb, oacc[nf2], 0, 0, 0);
      }
    }
  }

  #pragma unroll
  for (int jr = 0; jr < 4; ++jr) {
    const int i = i4 + jr;
    if (i >= NPIX) continue;
    const float inv = 1.f / lrun[jr];
    #pragma unroll
    for (int nf2 = 0; nf2 < 2; ++nf2) {
      const int m = h * HDIM + nf2 * 16 + (l & 15);
      oT[((size_t)b * NPIX + i) * MID + m] = oacc[nf2][jr] * inv;
    }
  }
}

// ---------------- output proj: [384x384] @ oT^T, hi/lo split for accuracy -----------
__global__ __launch_bounds__(256) void proj_gemm(
    const u16* __restrict__ wp_hi, const u16* __restrict__ wp_lo, const float* __restrict__ bp,
    const float* __restrict__ oT, float* __restrict__ out)
{
  __shared__ u16 Ah[128 * 32];
  __shared__ u16 Al[128 * 32];
  __shared__ u16 Bh[64 * 32];
  __shared__ u16 Bl[64 * 32];
  const int b = blockIdx.z;
  const int m0 = blockIdx.x * 128;
  const int n0 = blockIdx.y * 64;
  const int tid = threadIdx.x, l = tid & 63, w = tid >> 6;
  const int wm = (w & 1) * 64, wn = (w >> 1) * 32;

  const f32x4 vzero = {0.f, 0.f, 0.f, 0.f};
  f32x4 acc[4][2];
  #pragma unroll
  for (int mi = 0; mi < 4; ++mi)
    #pragma unroll
    for (int ni = 0; ni < 2; ++ni) acc[mi][ni] = vzero;

  for (int kt = 0; kt < 12; ++kt) {
    __syncthreads();
    #pragma unroll
    for (int s = 0; s < 2; ++s) {
      const int o = w * 2048 + s * 1024 + l * 16;
      const int row = o >> 6;
      const int c = ((o >> 4) & 3) ^ ((row >> 1) & 3);
      const size_t goff = (size_t)(m0 + row) * MID + kt * 32 + c * 8;
      GLL16(wp_hi + goff, (char*)Ah + w * 2048 + s * 1024);
      GLL16(wp_lo + goff, (char*)Al + w * 2048 + s * 1024);
    }
    {   // reg-stage B from f32 oT, split hi/lo
      const int row = tid >> 2;
      const int c = (tid & 3) ^ ((row >> 1) & 3);
      int nr = n0 + row; nr = nr > NPIX - 1 ? NPIX - 1 : nr;
      const float* g = oT + ((size_t)b * NPIX + nr) * MID + kt * 32 + c * 8;
      const float4 x0 = *(const float4*)g;
      const float4 x1 = *(const float4*)(g + 4);
      const float vv[8] = {x0.x, x0.y, x0.z, x0.w, x1.x, x1.y, x1.z, x1.w};
      bf16x8 hh, ll;
      #pragma unroll
      for (int e = 0; e < 8; ++e) {
        const u16 hb = f2bf(vv[e]);
        hh[e] = (short)hb;
        ll[e] = (short)f2bf(vv[e] - bf2f(hb));
      }
      *(bf16x8*)((char*)Bh + tid * 16) = hh;
      *(bf16x8*)((char*)Bl + tid * 16) = ll;
    }
    __syncthreads();
    bf16x8 ah[4], al[4], bh[2], bl[2];
    #pragma unroll
    for (int mi = 0; mi < 4; ++mi) {
      const int row = wm + mi * 16 + (l & 15);
      const int byte = row * 64 + (((l >> 4) ^ ((row >> 1) & 3)) << 4);
      ah[mi] = *(const bf16x8*)((const char*)Ah + byte);
      al[mi] = *(const bf16x8*)((const char*)Al + byte);
    }
    #pragma unroll
    for (int ni = 0; ni < 2; ++ni) {
      const int row = wn + ni * 16 + (l & 15);
      const int byte = row * 64 + (((l >> 4) ^ ((row >> 1) & 3)) << 4);
      bh[ni] = *(const bf16x8*)((const char*)Bh + byte);
      bl[ni] = *(const bf16x8*)((const char*)Bl + byte);
    }
    #pragma unroll
    for (int mi = 0; mi < 4; ++mi)
      #pragma unroll
      for (int ni = 0; ni < 2; ++ni) {
        acc[mi][ni] = __builtin_amdgcn_mfma_f32_16x16x32_bf16(ah[mi], bh[ni], acc[mi][ni], 0, 0, 0);
        acc[mi][ni] = __builtin_amdgcn_mfma_f32_16x16x32_bf16(al[mi], bh[ni], acc[mi][ni], 0, 0, 0);
        acc[mi][ni] = __builtin_amdgcn_mfma_f32_16x16x32_bf16(ah[mi], bl[ni], acc[mi][ni], 0, 0, 0);
      }
  }

  #pragma unroll
  for (int mi = 0; mi < 4; ++mi) {
    const int o0 = m0 + wm + mi * 16 + ((l >> 4) << 2);
    #pragma unroll
    for (int ni = 0; ni < 2; ++ni) {
      const int n = n0 + wn + ni * 16 + (l & 15);
      if (n >= NPIX) continue;
      #pragma unroll
      for (int jr = 0; jr < 4; ++jr)
        out[((size_t)b * MID + o0 + jr) * NPIX + n] = acc[mi][ni][jr] + bp[o0 + jr];
    }
  }
}

extern "C" void kernel_launch(void* const* d_in, const int* in_sizes, int n_in,
                              void* d_out, int out_size, void* d_ws, size_t ws_size,
                              hipStream_t stream) {
  const float* x          = (const float*)d_in[0];
  const float* Wq         = (const float*)d_in[1];
  const float* bq         = (const float*)d_in[2];
  const float* Wkv        = (const float*)d_in[3];
  const float* bkv        = (const float*)d_in[4];
  const float* bias_table = (const float*)d_in[5];
  const float* Wproj      = (const float*)d_in[6];
  const float* bproj      = (const float*)d_in[7];
  const float* gamma      = (const float*)d_in[8];
  const int*   rel_index  = (const int*)d_in[9];

  char* ws = (char*)d_ws;
  u16*   xT    = (u16*)(ws + 0);          //  9,633,792 B
  u16*   wqkv  = (u16*)(ws + 9633792);    //    884,736 B
  u16*   wp_hi = (u16*)(ws + 10518528);   //    294,912 B
  u16*   wp_lo = (u16*)(ws + 10813440);   //    294,912 B
  float* bqkv  = (float*)(ws + 11108352); //      4,608 B
  float* bp    = (float*)(ws + 11112960); //      1,536 B
  u16*   q_s   = (u16*)(ws + 11114496);   //  9,633,792 B
  u16*   k_s   = (u16*)(ws + 20748288);   //  9,633,792 B
  u16*   vt    = (u16*)(ws + 30382080);   //  9,633,792 B
  float* oT    = (float*)(ws + 40015872); // 19,267,584 B  (total ~56.6 MB)
  float* out   = (float*)d_out;

  prep_weights<<<dim3(1024), dim3(256), 0, stream>>>(Wq, bq, Wkv, bkv, Wproj, bproj, gamma,
                                                     wqkv, wp_hi, wp_lo, bqkv, bp);
  prep_x<<<dim3(25, 12, 16), dim3(32, 8), 0, stream>>>(x, xT);
  qkv_gemm<<<dim3(9, 13, 16), dim3(256), 0, stream>>>(wqkv, bqkv, xT, q_s, k_s, vt);
  attn<<<dim3(13, 12, 16), dim3(256), 0, stream>>>(q_s, k_s, vt, rel_index, bias_table, oT);
  proj_gemm<<<dim3(3, 13, 16), dim3(256), 0, stream>>>(wp_hi, wp_lo, bp, oT, out);
}

// Round 2
// 153.572 us; speedup vs baseline: 1.4402x; 1.4402x over previous
//
#include <hip/hip_runtime.h>
#include <hip/hip_bf16.h>

#define NPIX   784
#define CIN    384
#define NHEADS 12
#define HDIM   32
#define MID    384
#define QKV_M  1152
#define SCALE  0.17677669529663687f
#define LOG2E  1.4426950408889634f
#define QSCALE (0.17677669529663687f * 1.4426950408889634f)
#define W1SZ   442368   // 1152*384
#define W2SZ   147456   // 384*384
#define NBIAS  3025     // 55*55

typedef __attribute__((ext_vector_type(8))) short bf16x8;
typedef __attribute__((ext_vector_type(4))) float f32x4;
typedef float f32x4u __attribute__((ext_vector_type(4), aligned(4)));
typedef __attribute__((ext_vector_type(4))) unsigned short ush4;
typedef unsigned short u16;
typedef unsigned int u32;

__device__ __forceinline__ u16 f2bf(float f) {
  union { float f; u32 u; } v; v.f = f;
  u32 u = v.u;
  u += 0x7fffu + ((u >> 16) & 1u);
  return (u16)(u >> 16);
}
__device__ __forceinline__ float bf2f(u16 h) {
  union { u32 u; float f; } v; v.u = ((u32)h) << 16;
  return v.f;
}

#define GLL16(gsrc, ldst) \
  __builtin_amdgcn_global_load_lds((const __attribute__((address_space(1))) void*)(gsrc), \
                                   (__attribute__((address_space(3))) void*)(ldst), 16, 0, 0)

// ---------------- prepass: weights -> bf16; biasT[h][3025] = bias_table^T * log2e ----
__global__ __launch_bounds__(256) void prep_weights(
    const float* __restrict__ Wq, const float* __restrict__ bq,
    const float* __restrict__ Wkv, const float* __restrict__ bkv,
    const float* __restrict__ Wproj, const float* __restrict__ bproj,
    const float* __restrict__ gamma, const float* __restrict__ bias_table,
    u16* __restrict__ wqkv, u16* __restrict__ wp_hi, u16* __restrict__ wp_lo,
    float* __restrict__ bqkv, float* __restrict__ bp, float* __restrict__ biasT)
{
  const int total = W1SZ + W2SZ + QKV_M + MID + NBIAS * NHEADS;
  for (int i = blockIdx.x * blockDim.x + threadIdx.x; i < total; i += gridDim.x * blockDim.x) {
    if (i < W1SZ) {
      const int m = i / CIN;
      const float v = (m < MID) ? Wq[i] * QSCALE : Wkv[i - W2SZ];
      wqkv[i] = f2bf(v);
    } else if (i < W1SZ + W2SZ) {
      const int j = i - W1SZ;
      const int o = j / MID;
      const float v = Wproj[j] * gamma[o];
      const u16 hb = f2bf(v);
      wp_hi[j] = hb;
      wp_lo[j] = f2bf(v - bf2f(hb));
    } else if (i < W1SZ + W2SZ + QKV_M) {
      const int m = i - W1SZ - W2SZ;
      bqkv[m] = (m < MID) ? bq[m] * QSCALE : bkv[m - MID];
    } else if (i < W1SZ + W2SZ + QKV_M + MID) {
      const int o = i - W1SZ - W2SZ - QKV_M;
      bp[o] = bproj[o] * gamma[o];
    } else {
      const int j = i - (W1SZ + W2SZ + QKV_M + MID);
      const int h = j / NBIAS, r = j - h * NBIAS;
      biasT[j] = bias_table[r * NHEADS + h] * LOG2E;
    }
  }
}

// ---------------- prepass: x [B][C][N] f32 -> xT [B][N][C] bf16 ----------------------
__global__ __launch_bounds__(256) void prep_x(const float* __restrict__ x, u16* __restrict__ xT) {
  __shared__ float tile[32][33];
  const int b = blockIdx.z, c0 = blockIdx.y * 32, n0 = blockIdx.x * 32;
  const int tx = threadIdx.x, ty = threadIdx.y;
  #pragma unroll
  for (int j = 0; j < 4; ++j) {
    const int c = c0 + ty + j * 8, n = n0 + tx;
    tile[ty + j * 8][tx] = (n < NPIX) ? x[((size_t)b * CIN + c) * NPIX + n] : 0.f;
  }
  __syncthreads();
  #pragma unroll
  for (int j = 0; j < 4; ++j) {
    const int n = n0 + ty + j * 8, c = c0 + tx;
    if (n < NPIX) xT[((size_t)b * NPIX + n) * CIN + c] = f2bf(tile[tx][ty + j * 8]);
  }
}

// ---------------- QKV GEMM: [1152x384] @ [384x784] per batch ------------------------
__global__ __launch_bounds__(256) void qkv_gemm(
    const u16* __restrict__ wqkv, const float* __restrict__ bqkv,
    const u16* __restrict__ xT,
    u16* __restrict__ q_s, u16* __restrict__ k_s, u16* __restrict__ vt)
{
  __shared__ u16 As[128 * 32];   // 64B rows, XOR chunk swizzle key=(row>>1)&3
  __shared__ u16 Bs[64 * 32];
  // XCD swizzle: 1872 blocks = 8 xcd * 2 grp * 117 (9 mt * 13 nt); same-b -> same XCD
  const int id = blockIdx.x;
  const int xc = id & 7, s0 = id >> 3;
  const int grp = s0 / 117, r = s0 - grp * 117;
  const int b = grp * 8 + xc;
  const int m0 = (r % 9) * 128;
  const int n0 = (r / 9) * 64;
  const int tid = threadIdx.x, l = tid & 63, w = tid >> 6;
  const int wm = (w & 1) * 64, wn = (w >> 1) * 32;

  const f32x4 vzero = {0.f, 0.f, 0.f, 0.f};
  f32x4 acc[4][2];
  #pragma unroll
  for (int mi = 0; mi < 4; ++mi)
    #pragma unroll
    for (int ni = 0; ni < 2; ++ni) acc[mi][ni] = vzero;

  for (int kt = 0; kt < 12; ++kt) {
    __syncthreads();
    #pragma unroll
    for (int s = 0; s < 2; ++s) {   // stage A: 8KB, wave-chunked
      const int o = w * 2048 + s * 1024 + l * 16;
      const int row = o >> 6;
      const int c = ((o >> 4) & 3) ^ ((row >> 1) & 3);
      const u16* g = wqkv + (size_t)(m0 + row) * CIN + kt * 32 + c * 8;
      GLL16(g, (char*)As + w * 2048 + s * 1024);
    }
    {                               // stage B: 4KB
      const int o = w * 1024 + l * 16;
      const int row = o >> 6;
      const int c = ((o >> 4) & 3) ^ ((row >> 1) & 3);
      int nr = n0 + row; nr = nr > NPIX - 1 ? NPIX - 1 : nr;
      const u16* g = xT + ((size_t)b * NPIX + nr) * CIN + kt * 32 + c * 8;
      GLL16(g, (char*)Bs + w * 1024);
    }
    __syncthreads();
    bf16x8 af[4], bfr[2];
    #pragma unroll
    for (int mi = 0; mi < 4; ++mi) {
      const int row = wm + mi * 16 + (l & 15);
      const int byte = row * 64 + (((l >> 4) ^ ((row >> 1) & 3)) << 4);
      af[mi] = *(const bf16x8*)((const char*)As + byte);
    }
    #pragma unroll
    for (int ni = 0; ni < 2; ++ni) {
      const int row = wn + ni * 16 + (l & 15);
      const int byte = row * 64 + (((l >> 4) ^ ((row >> 1) & 3)) << 4);
      bfr[ni] = *(const bf16x8*)((const char*)Bs + byte);
    }
    #pragma unroll
    for (int mi = 0; mi < 4; ++mi)
      #pragma unroll
      for (int ni = 0; ni < 2; ++ni)
        acc[mi][ni] = __builtin_amdgcn_mfma_f32_16x16x32_bf16(af[mi], bfr[ni], acc[mi][ni], 0, 0, 0);
  }

  #pragma unroll
  for (int mi = 0; mi < 4; ++mi) {
    const int mrow0 = m0 + wm + mi * 16 + ((l >> 4) << 2);
    #pragma unroll
    for (int ni = 0; ni < 2; ++ni) {
      const int n = n0 + wn + ni * 16 + (l & 15);
      if (n >= NPIX) continue;
      const float v0 = acc[mi][ni][0] + bqkv[mrow0 + 0];
      const float v1 = acc[mi][ni][1] + bqkv[mrow0 + 1];
      const float v2 = acc[mi][ni][2] + bqkv[mrow0 + 2];
      const float v3 = acc[mi][ni][3] + bqkv[mrow0 + 3];
      if (mrow0 < MID) {
        const int h = mrow0 >> 5, d = mrow0 & 31;
        ush4 pk; pk[0] = f2bf(v0); pk[1] = f2bf(v1); pk[2] = f2bf(v2); pk[3] = f2bf(v3);
        *(ush4*)(q_s + (((size_t)b * NHEADS + h) * NPIX + n) * HDIM + d) = pk;
      } else if (mrow0 < 2 * MID) {
        const int m2 = mrow0 - MID, h = m2 >> 5, d = m2 & 31;
        ush4 pk; pk[0] = f2bf(v0); pk[1] = f2bf(v1); pk[2] = f2bf(v2); pk[3] = f2bf(v3);
        *(ush4*)(k_s + (((size_t)b * NHEADS + h) * NPIX + n) * HDIM + d) = pk;
      } else {
        const int m2 = mrow0 - 2 * MID, h = m2 >> 5, d = m2 & 31;
        u16* p = vt + (((size_t)b * NHEADS + h) * HDIM + d) * NPIX + n;
        p[0] = f2bf(v0); p[NPIX] = f2bf(v1); p[2 * NPIX] = f2bf(v2); p[3 * NPIX] = f2bf(v3);
      }
    }
  }
}

// ---------------- flash attention, arithmetic rel-pos bias (vectorized) -------------
__global__ __launch_bounds__(256) void attn(
    const u16* __restrict__ q_s, const u16* __restrict__ k_s, const u16* __restrict__ vt,
    const float* __restrict__ biasT, float* __restrict__ oT)
{
  __shared__ u16 Ks[64 * 32];      // [kv][d], 64B rows, key=(row>>1)&3
  __shared__ u16 Vs[32 * 64];      // [d][kv], 128B rows, key=row&7
  __shared__ u16 Ps[4][16 * 64];   // per-wave P, 128B rows, key=row&7
  // XCD swizzle: 2496 blocks = 8 xcd * 24 grp * 13 qt; same (b,h) -> same XCD
  const int id = blockIdx.x;
  const int xc = id & 7, s0 = id >> 3;
  const int grp = s0 / 13, qt = s0 - grp * 13;
  const int bh = grp * 8 + xc;
  const int h = bh % NHEADS, b = bh / NHEADS;
  const int tid = threadIdx.x, l = tid & 63, w = tid >> 6;
  const int qbase = qt * 64 + w * 16;
  const float* biasTh = biasT + h * NBIAS;

  int qrow = qbase + (l & 15); qrow = qrow > NPIX - 1 ? NPIX - 1 : qrow;
  const bf16x8 qf = *(const bf16x8*)(q_s + ((size_t)bh * NPIX + qrow) * HDIM + ((l >> 4) << 3));

  const f32x4 vzero = {0.f, 0.f, 0.f, 0.f};
  f32x4 oacc[2]; oacc[0] = vzero; oacc[1] = vzero;
  float mrun[4], lrun[4];
  #pragma unroll
  for (int jr = 0; jr < 4; ++jr) { mrun[jr] = -1e30f; lrun[jr] = 0.f; }
  const int i4 = qbase + ((l >> 4) << 2);
  const int i4c = i4 > NPIX - 4 ? NPIX - 4 : i4;
  const int yi = (int)((unsigned)i4c / 28u);
  const int xi = i4c - yi * 28;
  const int base0 = yi * 55 + xi + 1512;   // 27*55+27 folded in; idx = base0 + jr - (yj*55+xj)

  for (int t = 0; t < 13; ++t) {
    const int kv0 = t * 64;
    __syncthreads();
    {   // stage K [64][32]
      const int o = w * 1024 + l * 16;
      const int row = o >> 6;
      const int c = ((o >> 4) & 3) ^ ((row >> 1) & 3);
      int rg = kv0 + row; rg = rg > NPIX - 1 ? NPIX - 1 : rg;
      const u16* g = k_s + ((size_t)bh * NPIX + rg) * HDIM + c * 8;
      GLL16(g, (char*)Ks + w * 1024);
    }
    {   // stage V [32][64]
      const int o = w * 1024 + l * 16;
      const int d = o >> 7;
      const int c = ((o >> 4) & 7) ^ (d & 7);
      int col = kv0 + c * 8; col = col > NPIX - 8 ? NPIX - 8 : col;
      const u16* g = vt + ((size_t)bh * HDIM + d) * NPIX + col;
      GLL16(g, (char*)Vs + w * 1024);
    }
    __syncthreads();

    f32x4 s[4];
    #pragma unroll
    for (int nf = 0; nf < 4; ++nf) {
      const int row = nf * 16 + (l & 15);
      const int byte = row * 64 + (((l >> 4) ^ ((row >> 1) & 3)) << 4);
      const bf16x8 kf = *(const bf16x8*)((const char*)Ks + byte);
      s[nf] = __builtin_amdgcn_mfma_f32_16x16x32_bf16(qf, kf, vzero, 0, 0, 0);
    }

    float pm[4], lg[4][4];
    #pragma unroll
    for (int jr = 0; jr < 4; ++jr) pm[jr] = -1e30f;
    #pragma unroll
    for (int nf = 0; nf < 4; ++nf) {
      const int j = kv0 + nf * 16 + (l & 15);
      const int jc = j > NPIX - 1 ? NPIX - 1 : j;
      const int yj = (int)((unsigned)jc / 28u);
      const int xj = jc - yj * 28;
      const int idx = base0 - (yj * 55 + xj);
      const f32x4u bv = *(const f32x4u*)(biasTh + idx);   // rows i4c..i4c+3, same j
      const bool jv = j < NPIX;
      #pragma unroll
      for (int jr = 0; jr < 4; ++jr) {
        float v = s[nf][jr] + bv[jr];
        v = jv ? v : -1e30f;
        lg[nf][jr] = v;
        pm[jr] = fmaxf(pm[jr], v);
      }
    }
    #pragma unroll
    for (int off = 1; off < 16; off <<= 1)
      #pragma unroll
      for (int jr = 0; jr < 4; ++jr)
        pm[jr] = fmaxf(pm[jr], __shfl_xor(pm[jr], off, 64));

    float corr[4], rs[4];
    #pragma unroll
    for (int jr = 0; jr < 4; ++jr) {
      const float mnew = fmaxf(mrun[jr], pm[jr]);
      corr[jr] = __builtin_amdgcn_exp2f(mrun[jr] - mnew);
      mrun[jr] = mnew;
      rs[jr] = 0.f;
    }
    #pragma unroll
    for (int nf = 0; nf < 4; ++nf) {
      #pragma unroll
      for (int jr = 0; jr < 4; ++jr) {
        const float p = __builtin_amdgcn_exp2f(lg[nf][jr] - mrun[jr]);
        rs[jr] += p;
        const int r = ((l >> 4) << 2) + jr;
        const int j = nf * 16 + (l & 15);
        const int byte = r * 128 + ((((j >> 3)) ^ (r & 7)) << 4) + (j & 7) * 2;
        *(u16*)((char*)Ps[w] + byte) = f2bf(p);
      }
    }
    #pragma unroll
    for (int off = 1; off < 16; off <<= 1)
      #pragma unroll
      for (int jr = 0; jr < 4; ++jr)
        rs[jr] += __shfl_xor(rs[jr], off, 64);
    #pragma unroll
    for (int jr = 0; jr < 4; ++jr) lrun[jr] = lrun[jr] * corr[jr] + rs[jr];
    #pragma unroll
    for (int nf2 = 0; nf2 < 2; ++nf2)
      #pragma unroll
      for (int jr = 0; jr < 4; ++jr) oacc[nf2][jr] *= corr[jr];

    #pragma unroll
    for (int kk = 0; kk < 2; ++kk) {   // PV
      const int pr = l & 15;
      const int pc = kk * 4 + (l >> 4);
      const int pbyte = pr * 128 + ((pc ^ (pr & 7)) << 4);
      const bf16x8 pa = *(const bf16x8*)((const char*)Ps[w] + pbyte);
      #pragma unroll
      for (int nf2 = 0; nf2 < 2; ++nf2) {
        const int d = nf2 * 16 + (l & 15);
        const int vbyte = d * 128 + ((pc ^ (d & 7)) << 4);
        const bf16x8 vb = *(const bf16x8*)((const char*)Vs + vbyte);
        oacc[nf2] = __builtin_amdgcn_mfma_f32_16x16x32_bf16(pa, vb, oacc[nf2], 0, 0, 0);
      }
    }
  }

  #pragma unroll
  for (int jr = 0; jr < 4; ++jr) {
    const int i = i4 + jr;
    if (i >= NPIX) continue;
    const float inv = 1.f / lrun[jr];
    #pragma unroll
    for (int nf2 = 0; nf2 < 2; ++nf2) {
      const int m = h * HDIM + nf2 * 16 + (l & 15);
      oT[((size_t)b * NPIX + i) * MID + m] = oacc[nf2][jr] * inv;
    }
  }
}

// ---------------- output proj: [384x384] @ oT^T, hi/lo split for accuracy -----------
__global__ __launch_bounds__(256) void proj_gemm(
    const u16* __restrict__ wp_hi, const u16* __restrict__ wp_lo, const float* __restrict__ bp,
    const float* __restrict__ oT, float* __restrict__ out)
{
  __shared__ u16 Ah[128 * 32];
  __shared__ u16 Al[128 * 32];
  __shared__ u16 Bh[64 * 32];
  __shared__ u16 Bl[64 * 32];
  // XCD swizzle: 624 blocks = 8 xcd * 2 grp * 39 (3 mt * 13 nt); same-b -> same XCD
  const int id = blockIdx.x;
  const int xc = id & 7, s0 = id >> 3;
  const int grp = s0 / 39, r = s0 - grp * 39;
  const int b = grp * 8 + xc;
  const int m0 = (r % 3) * 128;
  const int n0 = (r / 3) * 64;
  const int tid = threadIdx.x, l = tid & 63, w = tid >> 6;
  const int wm = (w & 1) * 64, wn = (w >> 1) * 32;

  const f32x4 vzero = {0.f, 0.f, 0.f, 0.f};
  f32x4 acc[4][2];
  #pragma unroll
  for (int mi = 0; mi < 4; ++mi)
    #pragma unroll
    for (int ni = 0; ni < 2; ++ni) acc[mi][ni] = vzero;

  for (int kt = 0; kt < 12; ++kt) {
    __syncthreads();
    #pragma unroll
    for (int s = 0; s < 2; ++s) {
      const int o = w * 2048 + s * 1024 + l * 16;
      const int row = o >> 6;
      const int c = ((o >> 4) & 3) ^ ((row >> 1) & 3);
      const size_t goff = (size_t)(m0 + row) * MID + kt * 32 + c * 8;
      GLL16(wp_hi + goff, (char*)Ah + w * 2048 + s * 1024);
      GLL16(wp_lo + goff, (char*)Al + w * 2048 + s * 1024);
    }
    {   // reg-stage B from f32 oT, split hi/lo
      const int row = tid >> 2;
      const int c = (tid & 3) ^ ((row >> 1) & 3);
      int nr = n0 + row; nr = nr > NPIX - 1 ? NPIX - 1 : nr;
      const float* g = oT + ((size_t)b * NPIX + nr) * MID + kt * 32 + c * 8;
      const float4 x0 = *(const float4*)g;
      const float4 x1 = *(const float4*)(g + 4);
      const float vv[8] = {x0.x, x0.y, x0.z, x0.w, x1.x, x1.y, x1.z, x1.w};
      bf16x8 hh, ll;
      #pragma unroll
      for (int e = 0; e < 8; ++e) {
        const u16 hb = f2bf(vv[e]);
        hh[e] = (short)hb;
        ll[e] = (short)f2bf(vv[e] - bf2f(hb));
      }
      *(bf16x8*)((char*)Bh + tid * 16) = hh;
      *(bf16x8*)((char*)Bl + tid * 16) = ll;
    }
    __syncthreads();
    bf16x8 ah[4], al[4], bh[2], bl[2];
    #pragma unroll
    for (int mi = 0; mi < 4; ++mi) {
      const int row = wm + mi * 16 + (l & 15);
      const int byte = row * 64 + (((l >> 4) ^ ((row >> 1) & 3)) << 4);
      ah[mi] = *(const bf16x8*)((const char*)Ah + byte);
      al[mi] = *(const bf16x8*)((const char*)Al + byte);
    }
    #pragma unroll
    for (int ni = 0; ni < 2; ++ni) {
      const int row = wn + ni * 16 + (l & 15);
      const int byte = row * 64 + (((l >> 4) ^ ((row >> 1) & 3)) << 4);
      bh[ni] = *(const bf16x8*)((const char*)Bh + byte);
      bl[ni] = *(const bf16x8*)((const char*)Bl + byte);
    }
    #pragma unroll
    for (int mi = 0; mi < 4; ++mi)
      #pragma unroll
      for (int ni = 0; ni < 2; ++ni) {
        acc[mi][ni] = __builtin_amdgcn_mfma_f32_16x16x32_bf16(ah[mi], bh[ni], acc[mi][ni], 0, 0, 0);
        acc[mi][ni] = __builtin_amdgcn_mfma_f32_16x16x32_bf16(al[mi], bh[ni], acc[mi][ni], 0, 0, 0);
        acc[mi][ni] = __builtin_amdgcn_mfma_f32_16x16x32_bf16(ah[mi], bl[ni], acc[mi][ni], 0, 0, 0);
      }
  }

  #pragma unroll
  for (int mi = 0; mi < 4; ++mi) {
    const int o0 = m0 + wm + mi * 16 + ((l >> 4) << 2);
    #pragma unroll
    for (int ni = 0; ni < 2; ++ni) {
      const int n = n0 + wn + ni * 16 + (l & 15);
      if (n >= NPIX) continue;
      #pragma unroll
      for (int jr = 0; jr < 4; ++jr)
        out[((size_t)b * MID + o0 + jr) * NPIX + n] = acc[mi][ni][jr] + bp[o0 + jr];
    }
  }
}

extern "C" void kernel_launch(void* const* d_in, const int* in_sizes, int n_in,
                              void* d_out, int out_size, void* d_ws, size_t ws_size,
                              hipStream_t stream) {
  const float* x          = (const float*)d_in[0];
  const float* Wq         = (const float*)d_in[1];
  const float* bq         = (const float*)d_in[2];
  const float* Wkv        = (const float*)d_in[3];
  const float* bkv        = (const float*)d_in[4];
  const float* bias_table = (const float*)d_in[5];
  const float* Wproj      = (const float*)d_in[6];
  const float* bproj      = (const float*)d_in[7];
  const float* gamma      = (const float*)d_in[8];

  char* ws = (char*)d_ws;
  u16*   xT    = (u16*)(ws + 0);          //  9,633,792 B
  u16*   wqkv  = (u16*)(ws + 9633792);    //    884,736 B
  u16*   wp_hi = (u16*)(ws + 10518528);   //    294,912 B
  u16*   wp_lo = (u16*)(ws + 10813440);   //    294,912 B
  float* bqkv  = (float*)(ws + 11108352); //      4,608 B
  float* bp    = (float*)(ws + 11112960); //      1,536 B
  float* biasT = (float*)(ws + 11114496); //    145,200 B (padded to 145,408)
  u16*   q_s   = (u16*)(ws + 11259904);   //  9,633,792 B
  u16*   k_s   = (u16*)(ws + 20893696);   //  9,633,792 B
  u16*   vt    = (u16*)(ws + 30527488);   //  9,633,792 B
  float* oT    = (float*)(ws + 40161280); // 19,267,584 B  (total ~59.4 MB)
  float* out   = (float*)d_out;

  prep_weights<<<dim3(1024), dim3(256), 0, stream>>>(Wq, bq, Wkv, bkv, Wproj, bproj, gamma,
                                                     bias_table, wqkv, wp_hi, wp_lo, bqkv, bp, biasT);
  prep_x<<<dim3(25, 12, 16), dim3(32, 8), 0, stream>>>(x, xT);
  qkv_gemm<<<dim3(1872), dim3(256), 0, stream>>>(wqkv, bqkv, xT, q_s, k_s, vt);
  attn<<<dim3(2496), dim3(256), 0, stream>>>(q_s, k_s, vt, biasT, oT);
  proj_gemm<<<dim3(624), dim3(256), 0, stream>>>(wp_hi, wp_lo, bp, oT, out);
}

// Round 3
// 115.245 us; speedup vs baseline: 1.9192x; 1.3326x over previous
//
#include <hip/hip_runtime.h>
#include <hip/hip_bf16.h>

#define NPIX   784
#define CIN    384
#define NHEADS 12
#define HDIM   32
#define MID    384
#define QKV_M  1152
#define SCALE  0.17677669529663687f
#define LOG2E  1.4426950408889634f
#define QSCALE (0.17677669529663687f * 1.4426950408889634f)
#define W1SZ   442368   // 1152*384
#define W2SZ   147456   // 384*384
#define NBIAS  3025     // 55*55

typedef __attribute__((ext_vector_type(8))) short bf16x8;
typedef __attribute__((ext_vector_type(4))) float f32x4;
typedef float f32x4u __attribute__((ext_vector_type(4), aligned(4)));
typedef __attribute__((ext_vector_type(4))) unsigned short ush4;
typedef __attribute__((ext_vector_type(2))) unsigned int u32x2;
typedef unsigned short u16;
typedef unsigned int u32;

__device__ __forceinline__ u16 f2bf(float f) {
  union { float f; u32 u; } v; v.f = f;
  u32 u = v.u;
  u += 0x7fffu + ((u >> 16) & 1u);
  return (u16)(u >> 16);
}
__device__ __forceinline__ float bf2f(u16 h) {
  union { u32 u; float f; } v; v.u = ((u32)h) << 16;
  return v.f;
}
__device__ __forceinline__ u32 cvtpk_bf16(float lo, float hi) {
  u32 r;
  asm("v_cvt_pk_bf16_f32 %0, %1, %2" : "=v"(r) : "v"(lo), "v"(hi));
  return r;
}

#define GLL16(gsrc, ldst) \
  __builtin_amdgcn_global_load_lds((const __attribute__((address_space(1))) void*)(gsrc), \
                                   (__attribute__((address_space(3))) void*)(ldst), 16, 0, 0)

// ---------------- prepass: weights -> bf16; biasT[h][3025] = bias_table^T * log2e ----
__global__ __launch_bounds__(256) void prep_weights(
    const float* __restrict__ Wq, const float* __restrict__ bq,
    const float* __restrict__ Wkv, const float* __restrict__ bkv,
    const float* __restrict__ Wproj, const float* __restrict__ bproj,
    const float* __restrict__ gamma, const float* __restrict__ bias_table,
    u16* __restrict__ wqkv, u16* __restrict__ wp_hi, u16* __restrict__ wp_lo,
    float* __restrict__ bqkv, float* __restrict__ bp, float* __restrict__ biasT)
{
  const int total = W1SZ + W2SZ + QKV_M + MID + NBIAS * NHEADS;
  for (int i = blockIdx.x * blockDim.x + threadIdx.x; i < total; i += gridDim.x * blockDim.x) {
    if (i < W1SZ) {
      const int m = i / CIN;
      const float v = (m < MID) ? Wq[i] * QSCALE : Wkv[i - W2SZ];
      wqkv[i] = f2bf(v);
    } else if (i < W1SZ + W2SZ) {
      const int j = i - W1SZ;
      const int o = j / MID;
      const float v = Wproj[j] * gamma[o];
      const u16 hb = f2bf(v);
      wp_hi[j] = hb;
      wp_lo[j] = f2bf(v - bf2f(hb));
    } else if (i < W1SZ + W2SZ + QKV_M) {
      const int m = i - W1SZ - W2SZ;
      bqkv[m] = (m < MID) ? bq[m] * QSCALE : bkv[m - MID];
    } else if (i < W1SZ + W2SZ + QKV_M + MID) {
      const int o = i - W1SZ - W2SZ - QKV_M;
      bp[o] = bproj[o] * gamma[o];
    } else {
      const int j = i - (W1SZ + W2SZ + QKV_M + MID);
      const int h = j / NBIAS, r = j - h * NBIAS;
      biasT[j] = bias_table[r * NHEADS + h] * LOG2E;
    }
  }
}

// ---------------- prepass: x [B][C][N] f32 -> xT [B][N][C] bf16 ----------------------
__global__ __launch_bounds__(256) void prep_x(const float* __restrict__ x, u16* __restrict__ xT) {
  __shared__ float tile[32][33];
  const int b = blockIdx.z, c0 = blockIdx.y * 32, n0 = blockIdx.x * 32;
  const int tx = threadIdx.x, ty = threadIdx.y;
  #pragma unroll
  for (int j = 0; j < 4; ++j) {
    const int c = c0 + ty + j * 8, n = n0 + tx;
    tile[ty + j * 8][tx] = (n < NPIX) ? x[((size_t)b * CIN + c) * NPIX + n] : 0.f;
  }
  __syncthreads();
  #pragma unroll
  for (int j = 0; j < 4; ++j) {
    const int n = n0 + ty + j * 8, c = c0 + tx;
    if (n < NPIX) xT[((size_t)b * NPIX + n) * CIN + c] = f2bf(tile[tx][ty + j * 8]);
  }
}

// ---------------- QKV GEMM: [1152x384] @ [384x784] per batch ------------------------
__global__ __launch_bounds__(256) void qkv_gemm(
    const u16* __restrict__ wqkv, const float* __restrict__ bqkv,
    const u16* __restrict__ xT,
    u16* __restrict__ q_s, u16* __restrict__ k_s, u16* __restrict__ vt)
{
  __shared__ u16 As[128 * 32];   // 64B rows, XOR chunk swizzle key=(row>>1)&3
  __shared__ u16 Bs[64 * 32];
  // XCD swizzle: 1872 blocks = 8 xcd * 2 grp * 117 (9 mt * 13 nt); same-b -> same XCD
  const int id = blockIdx.x;
  const int xc = id & 7, s0 = id >> 3;
  const int grp = s0 / 117, r = s0 - grp * 117;
  const int b = grp * 8 + xc;
  const int m0 = (r % 9) * 128;
  const int n0 = (r / 9) * 64;
  const int tid = threadIdx.x, l = tid & 63, w = tid >> 6;
  const int wm = (w & 1) * 64, wn = (w >> 1) * 32;

  const f32x4 vzero = {0.f, 0.f, 0.f, 0.f};
  f32x4 acc[4][2];
  #pragma unroll
  for (int mi = 0; mi < 4; ++mi)
    #pragma unroll
    for (int ni = 0; ni < 2; ++ni) acc[mi][ni] = vzero;

  for (int kt = 0; kt < 12; ++kt) {
    __syncthreads();
    #pragma unroll
    for (int s = 0; s < 2; ++s) {   // stage A: 8KB, wave-chunked
      const int o = w * 2048 + s * 1024 + l * 16;
      const int row = o >> 6;
      const int c = ((o >> 4) & 3) ^ ((row >> 1) & 3);
      const u16* g = wqkv + (size_t)(m0 + row) * CIN + kt * 32 + c * 8;
      GLL16(g, (char*)As + w * 2048 + s * 1024);
    }
    {                               // stage B: 4KB
      const int o = w * 1024 + l * 16;
      const int row = o >> 6;
      const int c = ((o >> 4) & 3) ^ ((row >> 1) & 3);
      int nr = n0 + row; nr = nr > NPIX - 1 ? NPIX - 1 : nr;
      const u16* g = xT + ((size_t)b * NPIX + nr) * CIN + kt * 32 + c * 8;
      GLL16(g, (char*)Bs + w * 1024);
    }
    __syncthreads();
    bf16x8 af[4], bfr[2];
    #pragma unroll
    for (int mi = 0; mi < 4; ++mi) {
      const int row = wm + mi * 16 + (l & 15);
      const int byte = row * 64 + (((l >> 4) ^ ((row >> 1) & 3)) << 4);
      af[mi] = *(const bf16x8*)((const char*)As + byte);
    }
    #pragma unroll
    for (int ni = 0; ni < 2; ++ni) {
      const int row = wn + ni * 16 + (l & 15);
      const int byte = row * 64 + (((l >> 4) ^ ((row >> 1) & 3)) << 4);
      bfr[ni] = *(const bf16x8*)((const char*)Bs + byte);
    }
    #pragma unroll
    for (int mi = 0; mi < 4; ++mi)
      #pragma unroll
      for (int ni = 0; ni < 2; ++ni)
        acc[mi][ni] = __builtin_amdgcn_mfma_f32_16x16x32_bf16(af[mi], bfr[ni], acc[mi][ni], 0, 0, 0);
  }

  #pragma unroll
  for (int mi = 0; mi < 4; ++mi) {
    const int mrow0 = m0 + wm + mi * 16 + ((l >> 4) << 2);
    #pragma unroll
    for (int ni = 0; ni < 2; ++ni) {
      const int n = n0 + wn + ni * 16 + (l & 15);
      if (n >= NPIX) continue;
      const float v0 = acc[mi][ni][0] + bqkv[mrow0 + 0];
      const float v1 = acc[mi][ni][1] + bqkv[mrow0 + 1];
      const float v2 = acc[mi][ni][2] + bqkv[mrow0 + 2];
      const float v3 = acc[mi][ni][3] + bqkv[mrow0 + 3];
      if (mrow0 < MID) {
        const int h = mrow0 >> 5, d = mrow0 & 31;
        ush4 pk; pk[0] = f2bf(v0); pk[1] = f2bf(v1); pk[2] = f2bf(v2); pk[3] = f2bf(v3);
        *(ush4*)(q_s + (((size_t)b * NHEADS + h) * NPIX + n) * HDIM + d) = pk;
      } else if (mrow0 < 2 * MID) {
        const int m2 = mrow0 - MID, h = m2 >> 5, d = m2 & 31;
        ush4 pk; pk[0] = f2bf(v0); pk[1] = f2bf(v1); pk[2] = f2bf(v2); pk[3] = f2bf(v3);
        *(ush4*)(k_s + (((size_t)b * NHEADS + h) * NPIX + n) * HDIM + d) = pk;
      } else {
        const int m2 = mrow0 - 2 * MID, h = m2 >> 5, d = m2 & 31;
        u16* p = vt + (((size_t)b * NHEADS + h) * HDIM + d) * NPIX + n;
        p[0] = f2bf(v0); p[NPIX] = f2bf(v1); p[2 * NPIX] = f2bf(v2); p[3 * NPIX] = f2bf(v3);
      }
    }
  }
}

// ---------------- flash attention: swapped QK^T, m=0 softmax, bias via MFMA C-in ----
__global__ __launch_bounds__(256) void attn(
    const u16* __restrict__ q_s, const u16* __restrict__ k_s, const u16* __restrict__ vt,
    const float* __restrict__ biasT, float* __restrict__ oT)
{
  __shared__ u16 Ks[64 * 32];      // [kv][d], 64B rows, key=(row>>1)&3
  __shared__ u16 Vs[32 * 64];      // [d][kv], 128B rows, key=row&7
  __shared__ u16 Ps[4][16 * 64];   // per-wave P [q][kv], 128B rows, chunk^=(q&7)
  // XCD swizzle: 2496 blocks = 8 xcd * 24 grp * 13 qt; same (b,h) -> same XCD
  const int id = blockIdx.x;
  const int xc = id & 7, s0i = id >> 3;
  const int grp = s0i / 13, qt = s0i - grp * 13;
  const int bh = grp * 8 + xc;
  const int h = bh % NHEADS, b = bh / NHEADS;
  const int tid = threadIdx.x, l = tid & 63, w = tid >> 6;
  const int g = l >> 4, qr = l & 15;
  const int qbase = qt * 64 + w * 16;
  const float* biasTh = biasT + h * NBIAS;

  int qrow = qbase + qr; qrow = qrow > NPIX - 1 ? NPIX - 1 : qrow;
  const bf16x8 qf = *(const bf16x8*)(q_s + ((size_t)bh * NPIX + qrow) * HDIM + g * 8);

  const int yi = (qrow * 2341) >> 16;          // qrow / 28
  const int ibase3 = qrow + 27 * yi + 1509;    // yi*55+xi+1512-3

  // P LDS byte addresses (within this wave's 2KB region), loop-invariant
  int addrW[4], addrR[2];
  #pragma unroll
  for (int nf = 0; nf < 4; ++nf)
    addrW[nf] = qr * 128 + ((((nf << 1) + (g >> 1)) ^ (qr & 7)) << 4) + (g & 1) * 8;
  #pragma unroll
  for (int kk = 0; kk < 2; ++kk)
    addrR[kk] = qr * 128 + (((kk * 4 + g) ^ (qr & 7)) << 4);

  const f32x4 vzero = {0.f, 0.f, 0.f, 0.f};
  f32x4 oacc[2]; oacc[0] = vzero; oacc[1] = vzero;
  float lsum = 0.f;
  char* PsW = (char*)Ps[w];
  const float NEGINF = -__builtin_inff();

  for (int t = 0; t < 13; ++t) {
    const int kv0 = t * 64;
    __syncthreads();
    {   // stage K [64][32]
      const int o = w * 1024 + l * 16;
      const int row = o >> 6;
      const int c = ((o >> 4) & 3) ^ ((row >> 1) & 3);
      int rg = kv0 + row; rg = rg > NPIX - 1 ? NPIX - 1 : rg;
      GLL16(k_s + ((size_t)bh * NPIX + rg) * HDIM + c * 8, (char*)Ks + w * 1024);
    }
    {   // stage V [32][64]
      const int o = w * 1024 + l * 16;
      const int d = o >> 7;
      const int c = ((o >> 4) & 7) ^ (d & 7);
      int col = kv0 + c * 8; col = col > NPIX - 8 ? NPIX - 8 : col;
      GLL16(vt + ((size_t)bh * HDIM + d) * NPIX + col, (char*)Vs + w * 1024);
    }

    // bias C-in fragments (independent of staged data; issue early)
    f32x4 bfrag[4];
    #pragma unroll
    for (int nf = 0; nf < 4; ++nf) {
      if (kv0 + nf * 16 <= 768) {          // scalar-uniform validity of this nf block
        const int j4 = kv0 + nf * 16 + g * 4;
        const int yj = (j4 * 2341) >> 16;
        const int idx = ibase3 - j4 - 27 * yj;
        const f32x4u bv = *(const f32x4u*)(biasTh + idx);
        bfrag[nf][0] = bv[3]; bfrag[nf][1] = bv[2];
        bfrag[nf][2] = bv[1]; bfrag[nf][3] = bv[0];
      } else {
        bfrag[nf][0] = NEGINF; bfrag[nf][1] = NEGINF;
        bfrag[nf][2] = NEGINF; bfrag[nf][3] = NEGINF;
      }
    }
    __syncthreads();

    // QK^T swapped: S[kv][q] fragments; bias enters as C-in
    #pragma unroll
    for (int nf = 0; nf < 4; ++nf) {
      const int row = nf * 16 + qr;
      const int byte = row * 64 + ((g ^ ((row >> 1) & 3)) << 4);
      const bf16x8 kf = *(const bf16x8*)((const char*)Ks + byte);
      const f32x4 s = __builtin_amdgcn_mfma_f32_16x16x32_bf16(kf, qf, bfrag[nf], 0, 0, 0);
      const float p0 = __builtin_amdgcn_exp2f(s[0]);
      const float p1 = __builtin_amdgcn_exp2f(s[1]);
      const float p2 = __builtin_amdgcn_exp2f(s[2]);
      const float p3 = __builtin_amdgcn_exp2f(s[3]);
      lsum += (p0 + p1) + (p2 + p3);
      u32x2 wpair;
      wpair[0] = cvtpk_bf16(p0, p1);
      wpair[1] = cvtpk_bf16(p2, p3);
      *(u32x2*)(PsW + addrW[nf]) = wpair;
    }

    // PV
    #pragma unroll
    for (int kk = 0; kk < 2; ++kk) {
      const bf16x8 pa = *(const bf16x8*)(PsW + addrR[kk]);
      #pragma unroll
      for (int nf2 = 0; nf2 < 2; ++nf2) {
        const int d = nf2 * 16 + qr;
        const int vbyte = d * 128 + (((kk * 4 + g) ^ (d & 7)) << 4);
        const bf16x8 vb = *(const bf16x8*)((const char*)Vs + vbyte);
        oacc[nf2] = __builtin_amdgcn_mfma_f32_16x16x32_bf16(pa, vb, oacc[nf2], 0, 0, 0);
      }
    }
  }

  // row-sum: lane holds partial of row q=qr; combine the 4 kv-quarters
  lsum += __shfl_xor(lsum, 16, 64);
  lsum += __shfl_xor(lsum, 32, 64);

  #pragma unroll
  for (int jr = 0; jr < 4; ++jr) {
    const int i = qbase + g * 4 + jr;
    const float rsum = __shfl(lsum, g * 4 + jr, 64);
    if (i >= NPIX) continue;
    const float inv = 1.f / rsum;
    #pragma unroll
    for (int nf2 = 0; nf2 < 2; ++nf2) {
      const int m = h * HDIM + nf2 * 16 + qr;
      oT[((size_t)b * NPIX + i) * MID + m] = oacc[nf2][jr] * inv;
    }
  }
}

// ---------------- output proj: [384x384] @ oT^T, hi/lo split for accuracy -----------
__global__ __launch_bounds__(256) void proj_gemm(
    const u16* __restrict__ wp_hi, const u16* __restrict__ wp_lo, const float* __restrict__ bp,
    const float* __restrict__ oT, float* __restrict__ out)
{
  __shared__ u16 Ah[128 * 32];
  __shared__ u16 Al[128 * 32];
  __shared__ u16 Bh[64 * 32];
  __shared__ u16 Bl[64 * 32];
  // XCD swizzle: 624 blocks = 8 xcd * 2 grp * 39 (3 mt * 13 nt); same-b -> same XCD
  const int id = blockIdx.x;
  const int xc = id & 7, s0 = id >> 3;
  const int grp = s0 / 39, r = s0 - grp * 39;
  const int b = grp * 8 + xc;
  const int m0 = (r % 3) * 128;
  const int n0 = (r / 3) * 64;
  const int tid = threadIdx.x, l = tid & 63, w = tid >> 6;
  const int wm = (w & 1) * 64, wn = (w >> 1) * 32;

  const f32x4 vzero = {0.f, 0.f, 0.f, 0.f};
  f32x4 acc[4][2];
  #pragma unroll
  for (int mi = 0; mi < 4; ++mi)
    #pragma unroll
    for (int ni = 0; ni < 2; ++ni) acc[mi][ni] = vzero;

  for (int kt = 0; kt < 12; ++kt) {
    __syncthreads();
    #pragma unroll
    for (int s = 0; s < 2; ++s) {
      const int o = w * 2048 + s * 1024 + l * 16;
      const int row = o >> 6;
      const int c = ((o >> 4) & 3) ^ ((row >> 1) & 3);
      const size_t goff = (size_t)(m0 + row) * MID + kt * 32 + c * 8;
      GLL16(wp_hi + goff, (char*)Ah + w * 2048 + s * 1024);
      GLL16(wp_lo + goff, (char*)Al + w * 2048 + s * 1024);
    }
    {   // reg-stage B from f32 oT, split hi/lo
      const int row = tid >> 2;
      const int c = (tid & 3) ^ ((row >> 1) & 3);
      int nr = n0 + row; nr = nr > NPIX - 1 ? NPIX - 1 : nr;
      const float* g = oT + ((size_t)b * NPIX + nr) * MID + kt * 32 + c * 8;
      const float4 x0 = *(const float4*)g;
      const float4 x1 = *(const float4*)(g + 4);
      const float vv[8] = {x0.x, x0.y, x0.z, x0.w, x1.x, x1.y, x1.z, x1.w};
      bf16x8 hh, ll;
      #pragma unroll
      for (int e = 0; e < 8; ++e) {
        const u16 hb = f2bf(vv[e]);
        hh[e] = (short)hb;
        ll[e] = (short)f2bf(vv[e] - bf2f(hb));
      }
      *(bf16x8*)((char*)Bh + tid * 16) = hh;
      *(bf16x8*)((char*)Bl + tid * 16) = ll;
    }
    __syncthreads();
    bf16x8 ah[4], al[4], bh[2], bl[2];
    #pragma unroll
    for (int mi = 0; mi < 4; ++mi) {
      const int row = wm + mi * 16 + (l & 15);
      const int byte = row * 64 + (((l >> 4) ^ ((row >> 1) & 3)) << 4);
      ah[mi] = *(const bf16x8*)((const char*)Ah + byte);
      al[mi] = *(const bf16x8*)((const char*)Al + byte);
    }
    #pragma unroll
    for (int ni = 0; ni < 2; ++ni) {
      const int row = wn + ni * 16 + (l & 15);
      const int byte = row * 64 + (((l >> 4) ^ ((row >> 1) & 3)) << 4);
      bh[ni] = *(const bf16x8*)((const char*)Bh + byte);
      bl[ni] = *(const bf16x8*)((const char*)Bl + byte);
    }
    #pragma unroll
    for (int mi = 0; mi < 4; ++mi)
      #pragma unroll
      for (int ni = 0; ni < 2; ++ni) {
        acc[mi][ni] = __builtin_amdgcn_mfma_f32_16x16x32_bf16(ah[mi], bh[ni], acc[mi][ni], 0, 0, 0);
        acc[mi][ni] = __builtin_amdgcn_mfma_f32_16x16x32_bf16(al[mi], bh[ni], acc[mi][ni], 0, 0, 0);
        acc[mi][ni] = __builtin_amdgcn_mfma_f32_16x16x32_bf16(ah[mi], bl[ni], acc[mi][ni], 0, 0, 0);
      }
  }

  #pragma unroll
  for (int mi = 0; mi < 4; ++mi) {
    const int o0 = m0 + wm + mi * 16 + ((l >> 4) << 2);
    #pragma unroll
    for (int ni = 0; ni < 2; ++ni) {
      const int n = n0 + wn + ni * 16 + (l & 15);
      if (n >= NPIX) continue;
      #pragma unroll
      for (int jr = 0; jr < 4; ++jr)
        out[((size_t)b * MID + o0 + jr) * NPIX + n] = acc[mi][ni][jr] + bp[o0 + jr];
    }
  }
}

extern "C" void kernel_launch(void* const* d_in, const int* in_sizes, int n_in,
                              void* d_out, int out_size, void* d_ws, size_t ws_size,
                              hipStream_t stream) {
  const float* x          = (const float*)d_in[0];
  const float* Wq         = (const float*)d_in[1];
  const float* bq         = (const float*)d_in[2];
  const float* Wkv        = (const float*)d_in[3];
  const float* bkv        = (const float*)d_in[4];
  const float* bias_table = (const float*)d_in[5];
  const float* Wproj      = (const float*)d_in[6];
  const float* bproj      = (const float*)d_in[7];
  const float* gamma      = (const float*)d_in[8];

  char* ws = (char*)d_ws;
  u16*   xT    = (u16*)(ws + 0);          //  9,633,792 B
  u16*   wqkv  = (u16*)(ws + 9633792);    //    884,736 B
  u16*   wp_hi = (u16*)(ws + 10518528);   //    294,912 B
  u16*   wp_lo = (u16*)(ws + 10813440);   //    294,912 B
  float* bqkv  = (float*)(ws + 11108352); //      4,608 B
  float* bp    = (float*)(ws + 11112960); //      1,536 B
  float* biasT = (float*)(ws + 11114496); //    145,200 B (padded to 145,408)
  u16*   q_s   = (u16*)(ws + 11259904);   //  9,633,792 B
  u16*   k_s   = (u16*)(ws + 20893696);   //  9,633,792 B
  u16*   vt    = (u16*)(ws + 30527488);   //  9,633,792 B
  float* oT    = (float*)(ws + 40161280); // 19,267,584 B  (total ~59.4 MB)
  float* out   = (float*)d_out;

  prep_weights<<<dim3(1024), dim3(256), 0, stream>>>(Wq, bq, Wkv, bkv, Wproj, bproj, gamma,
                                                     bias_table, wqkv, wp_hi, wp_lo, bqkv, bp, biasT);
  prep_x<<<dim3(25, 12, 16), dim3(32, 8), 0, stream>>>(x, xT);
  qkv_gemm<<<dim3(1872), dim3(256), 0, stream>>>(wqkv, bqkv, xT, q_s, k_s, vt);
  attn<<<dim3(2496), dim3(256), 0, stream>>>(q_s, k_s, vt, biasT, oT);
  proj_gemm<<<dim3(624), dim3(256), 0, stream>>>(wp_hi, wp_lo, bp, oT, out);
}

// Round 4
// 102.362 us; speedup vs baseline: 2.1607x; 1.1259x over previous
//
#include <hip/hip_runtime.h>
#include <hip/hip_bf16.h>

#define NPIX   784
#define CIN    384
#define NHEADS 12
#define HDIM   32
#define MID    384
#define QKV_M  1152
#define SCALE  0.17677669529663687f
#define LOG2E  1.4426950408889634f
#define QSCALE (0.17677669529663687f * 1.4426950408889634f)
#define W1SZ   442368   // 1152*384
#define W2SZ   147456   // 384*384
#define NBIAS  3025     // 55*55

typedef __attribute__((ext_vector_type(8))) short bf16x8;
typedef __attribute__((ext_vector_type(4))) float f32x4;
typedef float f32x4u __attribute__((ext_vector_type(4), aligned(4)));
typedef __attribute__((ext_vector_type(4))) unsigned short ush4;
typedef __attribute__((ext_vector_type(2))) unsigned int u32x2;
typedef unsigned short u16;
typedef unsigned int u32;

__device__ __forceinline__ u16 f2bf(float f) {
  union { float f; u32 u; } v; v.f = f;
  u32 u = v.u;
  u += 0x7fffu + ((u >> 16) & 1u);
  return (u16)(u >> 16);
}
__device__ __forceinline__ u32 cvtpk_bf16(float lo, float hi) {
  u32 r;
  asm("v_cvt_pk_bf16_f32 %0, %1, %2" : "=v"(r) : "v"(lo), "v"(hi));
  return r;
}

#define GLL16(gsrc, ldst) \
  __builtin_amdgcn_global_load_lds((const __attribute__((address_space(1))) void*)(gsrc), \
                                   (__attribute__((address_space(3))) void*)(ldst), 16, 0, 0)

// ---------------- prepass: weights -> bf16; biasT flipped: biasT[h][k]=orig[3024-k]*log2e
__global__ __launch_bounds__(256) void prep_weights(
    const float* __restrict__ Wq, const float* __restrict__ bq,
    const float* __restrict__ Wkv, const float* __restrict__ bkv,
    const float* __restrict__ Wproj, const float* __restrict__ bproj,
    const float* __restrict__ gamma, const float* __restrict__ bias_table,
    u16* __restrict__ wqkv, u16* __restrict__ wp,
    float* __restrict__ bqkv, float* __restrict__ bp, float* __restrict__ biasT)
{
  const int total = W1SZ + W2SZ + QKV_M + MID + NBIAS * NHEADS;
  for (int i = blockIdx.x * blockDim.x + threadIdx.x; i < total; i += gridDim.x * blockDim.x) {
    if (i < W1SZ) {
      const int m = i / CIN;
      const float v = (m < MID) ? Wq[i] * QSCALE : Wkv[i - W2SZ];
      wqkv[i] = f2bf(v);
    } else if (i < W1SZ + W2SZ) {
      const int j = i - W1SZ;
      const int o = j / MID;
      wp[j] = f2bf(Wproj[j] * gamma[o]);
    } else if (i < W1SZ + W2SZ + QKV_M) {
      const int m = i - W1SZ - W2SZ;
      bqkv[m] = (m < MID) ? bq[m] * QSCALE : bkv[m - MID];
    } else if (i < W1SZ + W2SZ + QKV_M + MID) {
      const int o = i - W1SZ - W2SZ - QKV_M;
      bp[o] = bproj[o] * gamma[o];
    } else {
      const int j = i - (W1SZ + W2SZ + QKV_M + MID);
      const int h = j / NBIAS, r = j - h * NBIAS;
      biasT[j] = bias_table[(3024 - r) * NHEADS + h] * LOG2E;
    }
  }
}

// ---------------- prepass: x [B][C][N] f32 -> xT [B][N][C] bf16 ----------------------
__global__ __launch_bounds__(256) void prep_x(const float* __restrict__ x, u16* __restrict__ xT) {
  __shared__ float tile[32][33];
  const int b = blockIdx.z, c0 = blockIdx.y * 32, n0 = blockIdx.x * 32;
  const int tx = threadIdx.x, ty = threadIdx.y;
  #pragma unroll
  for (int j = 0; j < 4; ++j) {
    const int c = c0 + ty + j * 8, n = n0 + tx;
    tile[ty + j * 8][tx] = (n < NPIX) ? x[((size_t)b * CIN + c) * NPIX + n] : 0.f;
  }
  __syncthreads();
  #pragma unroll
  for (int j = 0; j < 4; ++j) {
    const int n = n0 + ty + j * 8, c = c0 + tx;
    if (n < NPIX) xT[((size_t)b * NPIX + n) * CIN + c] = f2bf(tile[tx][ty + j * 8]);
  }
}

// ---------------- QKV GEMM: [1152x384] @ [384x784] per batch, dbuf single-barrier ----
__global__ __launch_bounds__(256) void qkv_gemm(
    const u16* __restrict__ wqkv, const float* __restrict__ bqkv,
    const u16* __restrict__ xT,
    u16* __restrict__ q_s, u16* __restrict__ k_s, u16* __restrict__ vt)
{
  __shared__ u16 As[2][128 * 32];   // 64B rows, XOR chunk swizzle key=(row>>1)&3
  __shared__ u16 Bs[2][64 * 32];
  // XCD swizzle: 1872 blocks = 8 xcd * 2 grp * 117 (9 mt * 13 nt); same-b -> same XCD
  const int id = blockIdx.x;
  const int xc = id & 7, s0 = id >> 3;
  const int grp = s0 / 117, r = s0 - grp * 117;
  const int b = grp * 8 + xc;
  const int m0 = (r % 9) * 128;
  const int n0 = (r / 9) * 64;
  const int tid = threadIdx.x, l = tid & 63, w = tid >> 6;
  const int wm = (w & 1) * 64, wn = (w >> 1) * 32;

  auto stage = [&](int kt, int buf) {
    #pragma unroll
    for (int s = 0; s < 2; ++s) {   // A: 8KB
      const int o = w * 2048 + s * 1024 + l * 16;
      const int row = o >> 6;
      const int c = ((o >> 4) & 3) ^ ((row >> 1) & 3);
      GLL16(wqkv + (size_t)(m0 + row) * CIN + kt * 32 + c * 8,
            (char*)As[buf] + w * 2048 + s * 1024);
    }
    {                               // B: 4KB
      const int o = w * 1024 + l * 16;
      const int row = o >> 6;
      const int c = ((o >> 4) & 3) ^ ((row >> 1) & 3);
      int nr = n0 + row; nr = nr > NPIX - 1 ? NPIX - 1 : nr;
      GLL16(xT + ((size_t)b * NPIX + nr) * CIN + kt * 32 + c * 8,
            (char*)Bs[buf] + w * 1024);
    }
  };

  const f32x4 vzero = {0.f, 0.f, 0.f, 0.f};
  f32x4 acc[4][2];
  #pragma unroll
  for (int mi = 0; mi < 4; ++mi)
    #pragma unroll
    for (int ni = 0; ni < 2; ++ni) acc[mi][ni] = vzero;

  stage(0, 0);
  for (int kt = 0; kt < 12; ++kt) {
    const int buf = kt & 1;
    __syncthreads();                 // drains vmcnt: buf ready; prev readers done
    if (kt < 11) stage(kt + 1, buf ^ 1);
    bf16x8 af[4], bfr[2];
    #pragma unroll
    for (int mi = 0; mi < 4; ++mi) {
      const int row = wm + mi * 16 + (l & 15);
      const int byte = row * 64 + (((l >> 4) ^ ((row >> 1) & 3)) << 4);
      af[mi] = *(const bf16x8*)((const char*)As[buf] + byte);
    }
    #pragma unroll
    for (int ni = 0; ni < 2; ++ni) {
      const int row = wn + ni * 16 + (l & 15);
      const int byte = row * 64 + (((l >> 4) ^ ((row >> 1) & 3)) << 4);
      bfr[ni] = *(const bf16x8*)((const char*)Bs[buf] + byte);
    }
    __builtin_amdgcn_s_setprio(1);
    #pragma unroll
    for (int mi = 0; mi < 4; ++mi)
      #pragma unroll
      for (int ni = 0; ni < 2; ++ni)
        acc[mi][ni] = __builtin_amdgcn_mfma_f32_16x16x32_bf16(af[mi], bfr[ni], acc[mi][ni], 0, 0, 0);
    __builtin_amdgcn_s_setprio(0);
  }

  #pragma unroll
  for (int mi = 0; mi < 4; ++mi) {
    const int mrow0 = m0 + wm + mi * 16 + ((l >> 4) << 2);
    #pragma unroll
    for (int ni = 0; ni < 2; ++ni) {
      const int n = n0 + wn + ni * 16 + (l & 15);
      if (n >= NPIX) continue;
      const float v0 = acc[mi][ni][0] + bqkv[mrow0 + 0];
      const float v1 = acc[mi][ni][1] + bqkv[mrow0 + 1];
      const float v2 = acc[mi][ni][2] + bqkv[mrow0 + 2];
      const float v3 = acc[mi][ni][3] + bqkv[mrow0 + 3];
      if (mrow0 < MID) {
        const int h = mrow0 >> 5, d = mrow0 & 31;
        ush4 pk; pk[0] = f2bf(v0); pk[1] = f2bf(v1); pk[2] = f2bf(v2); pk[3] = f2bf(v3);
        *(ush4*)(q_s + (((size_t)b * NHEADS + h) * NPIX + n) * HDIM + d) = pk;
      } else if (mrow0 < 2 * MID) {
        const int m2 = mrow0 - MID, h = m2 >> 5, d = m2 & 31;
        ush4 pk; pk[0] = f2bf(v0); pk[1] = f2bf(v1); pk[2] = f2bf(v2); pk[3] = f2bf(v3);
        *(ush4*)(k_s + (((size_t)b * NHEADS + h) * NPIX + n) * HDIM + d) = pk;
      } else {
        const int m2 = mrow0 - 2 * MID, h = m2 >> 5, d = m2 & 31;
        u16* p = vt + (((size_t)b * NHEADS + h) * HDIM + d) * NPIX + n;
        p[0] = f2bf(v0); p[NPIX] = f2bf(v1); p[2 * NPIX] = f2bf(v2); p[3 * NPIX] = f2bf(v3);
      }
    }
  }
}

// ---------------- flash attention: swapped QK^T, m=0 softmax, dbuf single-barrier ----
__global__ __launch_bounds__(256) void attn(
    const u16* __restrict__ q_s, const u16* __restrict__ k_s, const u16* __restrict__ vt,
    const float* __restrict__ biasT, u16* __restrict__ oTb)
{
  __shared__ u16 Ks[2][64 * 32];   // [kv][d], 64B rows, key=(row>>1)&3
  __shared__ u16 Vs[2][32 * 64];   // [d][kv], 128B rows, key=row&7
  __shared__ u16 Ps[4][16 * 64];   // per-wave P [q][kv], 128B rows, chunk^=(q&7)
  // XCD swizzle: 2496 blocks = 8 xcd * 24 grp * 13 qt; same (b,h) -> same XCD
  const int id = blockIdx.x;
  const int xc = id & 7, s0i = id >> 3;
  const int grp = s0i / 13, qt = s0i - grp * 13;
  const int bh = grp * 8 + xc;
  const int h = bh % NHEADS, b = bh / NHEADS;
  const int tid = threadIdx.x, l = tid & 63, w = tid >> 6;
  const int g = l >> 4, qr = l & 15;
  const int qbase = qt * 64 + w * 16;
  const float* biasTh = biasT + h * NBIAS;

  int qrow = qbase + qr; qrow = qrow > NPIX - 1 ? NPIX - 1 : qrow;
  const bf16x8 qf = *(const bf16x8*)(q_s + ((size_t)bh * NPIX + qrow) * HDIM + g * 8);

  const int yi = (qrow * 2341) >> 16;          // qrow / 28
  const int fbase = 1512 - qrow - 27 * yi;     // flipped-table base: idx = fbase + j4 + 27*yj

  // P LDS byte addresses (within this wave's 2KB region), loop-invariant
  int addrW[4], addrR[2];
  #pragma unroll
  for (int nf = 0; nf < 4; ++nf)
    addrW[nf] = qr * 128 + ((((nf << 1) + (g >> 1)) ^ (qr & 7)) << 4) + (g & 1) * 8;
  #pragma unroll
  for (int kk = 0; kk < 2; ++kk)
    addrR[kk] = qr * 128 + (((kk * 4 + g) ^ (qr & 7)) << 4);

  auto stage = [&](int kv0, int buf) {
    const int o = w * 1024 + l * 16;
    {   // K [64][32]
      const int row = o >> 6;
      const int c = ((o >> 4) & 3) ^ ((row >> 1) & 3);
      int rg = kv0 + row; rg = rg > NPIX - 1 ? NPIX - 1 : rg;
      GLL16(k_s + ((size_t)bh * NPIX + rg) * HDIM + c * 8, (char*)Ks[buf] + w * 1024);
    }
    {   // V [32][64]
      const int d = o >> 7;
      const int c = ((o >> 4) & 7) ^ (d & 7);
      int col = kv0 + c * 8; col = col > NPIX - 8 ? NPIX - 8 : col;
      GLL16(vt + ((size_t)bh * HDIM + d) * NPIX + col, (char*)Vs[buf] + w * 1024);
    }
  };

  const f32x4 vzero = {0.f, 0.f, 0.f, 0.f};
  f32x4 oacc[2]; oacc[0] = vzero; oacc[1] = vzero;
  float lsum = 0.f;
  char* PsW = (char*)Ps[w];
  const float NEGINF = -__builtin_inff();

  stage(0, 0);
  for (int t = 0; t < 13; ++t) {
    const int kv0 = t * 64;
    const int buf = t & 1;

    // bias C-in fragments: issue loads before the barrier (latency hides in wait)
    f32x4 bfrag[4];
    #pragma unroll
    for (int nf = 0; nf < 4; ++nf) {
      if (kv0 + nf * 16 <= 768) {              // uniform validity of this nf block
        const int j4 = kv0 + nf * 16 + g * 4;
        const int yj = (j4 * 2341) >> 16;
        const int idx = fbase + j4 + 27 * yj;
        const f32x4u bv = *(const f32x4u*)(biasTh + idx);
        bfrag[nf] = (f32x4){bv[0], bv[1], bv[2], bv[3]};
      } else {
        bfrag[nf] = (f32x4){NEGINF, NEGINF, NEGINF, NEGINF};
      }
    }

    __syncthreads();                            // buf staged; prev readers done
    if (t < 12) stage(kv0 + 64, buf ^ 1);

    // QK^T swapped, clustered MFMA; bias enters as C-in
    f32x4 s[4];
    __builtin_amdgcn_s_setprio(1);
    #pragma unroll
    for (int nf = 0; nf < 4; ++nf) {
      const int row = nf * 16 + qr;
      const int byte = row * 64 + ((g ^ ((row >> 1) & 3)) << 4);
      const bf16x8 kf = *(const bf16x8*)((const char*)Ks[buf] + byte);
      s[nf] = __builtin_amdgcn_mfma_f32_16x16x32_bf16(kf, qf, bfrag[nf], 0, 0, 0);
    }
    __builtin_amdgcn_s_setprio(0);

    #pragma unroll
    for (int nf = 0; nf < 4; ++nf) {
      const float p0 = __builtin_amdgcn_exp2f(s[nf][0]);
      const float p1 = __builtin_amdgcn_exp2f(s[nf][1]);
      const float p2 = __builtin_amdgcn_exp2f(s[nf][2]);
      const float p3 = __builtin_amdgcn_exp2f(s[nf][3]);
      lsum += (p0 + p1) + (p2 + p3);
      u32x2 wpair;
      wpair[0] = cvtpk_bf16(p0, p1);
      wpair[1] = cvtpk_bf16(p2, p3);
      *(u32x2*)(PsW + addrW[nf]) = wpair;
    }

    // PV
    __builtin_amdgcn_s_setprio(1);
    #pragma unroll
    for (int kk = 0; kk < 2; ++kk) {
      const bf16x8 pa = *(const bf16x8*)(PsW + addrR[kk]);
      #pragma unroll
      for (int nf2 = 0; nf2 < 2; ++nf2) {
        const int d = nf2 * 16 + qr;
        const int vbyte = d * 128 + (((kk * 4 + g) ^ (d & 7)) << 4);
        const bf16x8 vb = *(const bf16x8*)((const char*)Vs[buf] + vbyte);
        oacc[nf2] = __builtin_amdgcn_mfma_f32_16x16x32_bf16(pa, vb, oacc[nf2], 0, 0, 0);
      }
    }
    __builtin_amdgcn_s_setprio(0);
  }

  // row-sum: combine the 4 kv-quarters
  lsum += __shfl_xor(lsum, 16, 64);
  lsum += __shfl_xor(lsum, 32, 64);

  #pragma unroll
  for (int jr = 0; jr < 4; ++jr) {
    const int i = qbase + g * 4 + jr;
    const float rsum = __shfl(lsum, g * 4 + jr, 64);
    if (i >= NPIX) continue;
    const float inv = 1.f / rsum;
    #pragma unroll
    for (int nf2 = 0; nf2 < 2; ++nf2) {
      const int m = h * HDIM + nf2 * 16 + qr;
      oTb[((size_t)b * NPIX + i) * MID + m] = f2bf(oacc[nf2][jr] * inv);
    }
  }
}

// ---------------- output proj: plain bf16 GEMM [384x384] @ oTb^T, dbuf --------------
__global__ __launch_bounds__(256) void proj_gemm(
    const u16* __restrict__ wp, const float* __restrict__ bp,
    const u16* __restrict__ oTb, float* __restrict__ out)
{
  __shared__ u16 Ah[2][128 * 32];
  __shared__ u16 Bh[2][64 * 32];
  // XCD swizzle: 624 blocks = 8 xcd * 2 grp * 39 (3 mt * 13 nt); same-b -> same XCD
  const int id = blockIdx.x;
  const int xc = id & 7, s0 = id >> 3;
  const int grp = s0 / 39, r = s0 - grp * 39;
  const int b = grp * 8 + xc;
  const int m0 = (r % 3) * 128;
  const int n0 = (r / 3) * 64;
  const int tid = threadIdx.x, l = tid & 63, w = tid >> 6;
  const int wm = (w & 1) * 64, wn = (w >> 1) * 32;

  auto stage = [&](int kt, int buf) {
    #pragma unroll
    for (int s = 0; s < 2; ++s) {
      const int o = w * 2048 + s * 1024 + l * 16;
      const int row = o >> 6;
      const int c = ((o >> 4) & 3) ^ ((row >> 1) & 3);
      GLL16(wp + (size_t)(m0 + row) * MID + kt * 32 + c * 8,
            (char*)Ah[buf] + w * 2048 + s * 1024);
    }
    {
      const int o = w * 1024 + l * 16;
      const int row = o >> 6;
      const int c = ((o >> 4) & 3) ^ ((row >> 1) & 3);
      int nr = n0 + row; nr = nr > NPIX - 1 ? NPIX - 1 : nr;
      GLL16(oTb + ((size_t)b * NPIX + nr) * MID + kt * 32 + c * 8,
            (char*)Bh[buf] + w * 1024);
    }
  };

  const f32x4 vzero = {0.f, 0.f, 0.f, 0.f};
  f32x4 acc[4][2];
  #pragma unroll
  for (int mi = 0; mi < 4; ++mi)
    #pragma unroll
    for (int ni = 0; ni < 2; ++ni) acc[mi][ni] = vzero;

  stage(0, 0);
  for (int kt = 0; kt < 12; ++kt) {
    const int buf = kt & 1;
    __syncthreads();
    if (kt < 11) stage(kt + 1, buf ^ 1);
    bf16x8 ah[4], bfr[2];
    #pragma unroll
    for (int mi = 0; mi < 4; ++mi) {
      const int row = wm + mi * 16 + (l & 15);
      const int byte = row * 64 + (((l >> 4) ^ ((row >> 1) & 3)) << 4);
      ah[mi] = *(const bf16x8*)((const char*)Ah[buf] + byte);
    }
    #pragma unroll
    for (int ni = 0; ni < 2; ++ni) {
      const int row = wn + ni * 16 + (l & 15);
      const int byte = row * 64 + (((l >> 4) ^ ((row >> 1) & 3)) << 4);
      bfr[ni] = *(const bf16x8*)((const char*)Bh[buf] + byte);
    }
    __builtin_amdgcn_s_setprio(1);
    #pragma unroll
    for (int mi = 0; mi < 4; ++mi)
      #pragma unroll
      for (int ni = 0; ni < 2; ++ni)
        acc[mi][ni] = __builtin_amdgcn_mfma_f32_16x16x32_bf16(ah[mi], bfr[ni], acc[mi][ni], 0, 0, 0);
    __builtin_amdgcn_s_setprio(0);
  }

  #pragma unroll
  for (int mi = 0; mi < 4; ++mi) {
    const int o0 = m0 + wm + mi * 16 + ((l >> 4) << 2);
    #pragma unroll
    for (int ni = 0; ni < 2; ++ni) {
      const int n = n0 + wn + ni * 16 + (l & 15);
      if (n >= NPIX) continue;
      #pragma unroll
      for (int jr = 0; jr < 4; ++jr)
        out[((size_t)b * MID + o0 + jr) * NPIX + n] = acc[mi][ni][jr] + bp[o0 + jr];
    }
  }
}

extern "C" void kernel_launch(void* const* d_in, const int* in_sizes, int n_in,
                              void* d_out, int out_size, void* d_ws, size_t ws_size,
                              hipStream_t stream) {
  const float* x          = (const float*)d_in[0];
  const float* Wq         = (const float*)d_in[1];
  const float* bq         = (const float*)d_in[2];
  const float* Wkv        = (const float*)d_in[3];
  const float* bkv        = (const float*)d_in[4];
  const float* bias_table = (const float*)d_in[5];
  const float* Wproj      = (const float*)d_in[6];
  const float* bproj      = (const float*)d_in[7];
  const float* gamma      = (const float*)d_in[8];

  char* ws = (char*)d_ws;
  u16*   xT    = (u16*)(ws + 0);          //  9,633,792 B
  u16*   wqkv  = (u16*)(ws + 9633792);    //    884,736 B
  u16*   wp    = (u16*)(ws + 10518528);   //    294,912 B
  float* bqkv  = (float*)(ws + 10813440); //      4,608 B
  float* bp    = (float*)(ws + 10818048); //      1,536 B
  float* biasT = (float*)(ws + 10819584); //    145,200 B (pad to 145,408)
  u16*   q_s   = (u16*)(ws + 10964992);   //  9,633,792 B
  u16*   k_s   = (u16*)(ws + 20598784);   //  9,633,792 B
  u16*   vt    = (u16*)(ws + 30232576);   //  9,633,792 B
  u16*   oTb   = (u16*)(ws + 39866368);   //  9,633,792 B  (total ~49.5 MB)
  float* out   = (float*)d_out;

  prep_weights<<<dim3(1024), dim3(256), 0, stream>>>(Wq, bq, Wkv, bkv, Wproj, bproj, gamma,
                                                     bias_table, wqkv, wp, bqkv, bp, biasT);
  prep_x<<<dim3(25, 12, 16), dim3(32, 8), 0, stream>>>(x, xT);
  qkv_gemm<<<dim3(1872), dim3(256), 0, stream>>>(wqkv, bqkv, xT, q_s, k_s, vt);
  attn<<<dim3(2496), dim3(256), 0, stream>>>(q_s, k_s, vt, biasT, oTb);
  proj_gemm<<<dim3(624), dim3(256), 0, stream>>>(wp, bp, oTb, out);
}

// Round 5
// 98.262 us; speedup vs baseline: 2.2509x; 1.0417x over previous
//
#include <hip/hip_runtime.h>
#include <hip/hip_bf16.h>

#define NPIX   784
#define CIN    384
#define NHEADS 12
#define HDIM   32
#define MID    384
#define QKV_M  1152
#define LOG2E  1.4426950408889634f
#define QSCALE (0.17677669529663687f * 1.4426950408889634f)
#define W1SZ   442368   // 1152*384
#define W2SZ   147456   // 384*384
#define NBIAS  3025     // 55*55

typedef __attribute__((ext_vector_type(8))) short bf16x8;
typedef __attribute__((ext_vector_type(4))) float f32x4;
typedef __attribute__((ext_vector_type(4))) unsigned short ush4;
typedef __attribute__((ext_vector_type(2))) unsigned int u32x2;
typedef unsigned short u16;
typedef unsigned int u32;

__device__ __forceinline__ u16 f2bf(float f) {
  union { float f; u32 u; } v; v.f = f;
  u32 u = v.u;
  u += 0x7fffu + ((u >> 16) & 1u);
  return (u16)(u >> 16);
}
__device__ __forceinline__ u32 cvtpk_bf16(float lo, float hi) {
  u32 r;
  asm("v_cvt_pk_bf16_f32 %0, %1, %2" : "=v"(r) : "v"(lo), "v"(hi));
  return r;
}
// untracked global loads (vmcnt managed manually by the attn protocol)
__device__ __forceinline__ f32x4 gload16f(const float* p) {
  f32x4 r;
  asm volatile("global_load_dwordx4 %0, %1, off" : "=v"(r) : "v"(p) : "memory");
  return r;
}
__device__ __forceinline__ bf16x8 gload16b(const u16* p) {
  bf16x8 r;
  asm volatile("global_load_dwordx4 %0, %1, off" : "=v"(r) : "v"(p) : "memory");
  return r;
}

#define GLL16(gsrc, ldst) \
  __builtin_amdgcn_global_load_lds((const __attribute__((address_space(1))) void*)(gsrc), \
                                   (__attribute__((address_space(3))) void*)(ldst), 16, 0, 0)

// ---------------- fused prepass: weights->bf16 + biasT(flipped) + x transpose -------
__global__ __launch_bounds__(256) void prep_all(
    const float* __restrict__ x,
    const float* __restrict__ Wq, const float* __restrict__ bq,
    const float* __restrict__ Wkv, const float* __restrict__ bkv,
    const float* __restrict__ Wproj, const float* __restrict__ bproj,
    const float* __restrict__ gamma, const float* __restrict__ bias_table,
    u16* __restrict__ wqkv, u16* __restrict__ wp,
    float* __restrict__ bqkv, float* __restrict__ bp, float* __restrict__ biasT,
    u16* __restrict__ xT)
{
  __shared__ float tile[32][65];
  const int bid = blockIdx.x;
  const int tid = threadIdx.x;
  if (bid < 256) {   // ---- weights part ----
    const int total = W1SZ + W2SZ + QKV_M + MID + NBIAS * NHEADS;
    for (int i = bid * 256 + tid; i < total; i += 256 * 256) {
      if (i < W1SZ) {
        const int m = i / CIN;
        const float v = (m < MID) ? Wq[i] * QSCALE : Wkv[i - W2SZ];
        wqkv[i] = f2bf(v);
      } else if (i < W1SZ + W2SZ) {
        const int j = i - W1SZ;
        const int o = j / MID;
        wp[j] = f2bf(Wproj[j] * gamma[o]);
      } else if (i < W1SZ + W2SZ + QKV_M) {
        const int m = i - W1SZ - W2SZ;
        bqkv[m] = (m < MID) ? bq[m] * QSCALE : bkv[m - MID];
      } else if (i < W1SZ + W2SZ + QKV_M + MID) {
        const int o = i - W1SZ - W2SZ - QKV_M;
        bp[o] = bproj[o] * gamma[o];
      } else {
        const int j = i - (W1SZ + W2SZ + QKV_M + MID);
        const int h = j / NBIAS, r = j - h * NBIAS;
        biasT[j] = bias_table[(3024 - r) * NHEADS + h] * LOG2E;
      }
    }
    return;
  }
  // ---- x transpose part: [B][C][N] f32 -> [B][N][C] bf16, 32c x 64n tiles ----
  const int tix = bid - 256;            // 0..2495 = 13 nt * 12 ct * 16 b
  const int nt = tix % 13;
  const int rem = tix / 13;
  const int ct = rem % 12, b = rem / 12;
  const int n0 = nt * 64, c0 = ct * 32;
  #pragma unroll
  for (int p = 0; p < 2; ++p) {
    const int r = p * 16 + (tid >> 4);
    const int cc = (tid & 15) * 4;
    int n = n0 + cc; if (n > NPIX - 4) n = NPIX - 4;
    const float4 v = *(const float4*)(x + ((size_t)b * CIN + c0 + r) * NPIX + n);
    tile[r][cc + 0] = v.x; tile[r][cc + 1] = v.y;
    tile[r][cc + 2] = v.z; tile[r][cc + 3] = v.w;
  }
  __syncthreads();
  const int n_l = tid >> 2, cq = tid & 3;
  const int n = n0 + n_l;
  if (n < NPIX) {
    float f[8];
    #pragma unroll
    for (int e = 0; e < 8; ++e) f[e] = tile[cq * 8 + e][n_l];
    union { u32 u[4]; bf16x8 v; } pk;
    pk.u[0] = cvtpk_bf16(f[0], f[1]);
    pk.u[1] = cvtpk_bf16(f[2], f[3]);
    pk.u[2] = cvtpk_bf16(f[4], f[5]);
    pk.u[3] = cvtpk_bf16(f[6], f[7]);
    *(bf16x8*)(xT + ((size_t)b * NPIX + n) * CIN + c0 + cq * 8) = pk.v;
  }
}

// ---------------- QKV GEMM: [1152x384] @ [384x784] per batch, dbuf single-barrier ----
__global__ __launch_bounds__(256) void qkv_gemm(
    const u16* __restrict__ wqkv, const float* __restrict__ bqkv,
    const u16* __restrict__ xT,
    u16* __restrict__ q_s, u16* __restrict__ k_s, u16* __restrict__ vt)
{
  __shared__ u16 As[2][128 * 32];   // 64B rows, XOR chunk swizzle key=(row>>1)&3
  __shared__ u16 Bs[2][64 * 32];
  // XCD swizzle: 1872 blocks = 8 xcd * 2 grp * 117 (9 mt * 13 nt); same-b -> same XCD
  const int id = blockIdx.x;
  const int xc = id & 7, s0 = id >> 3;
  const int grp = s0 / 117, r = s0 - grp * 117;
  const int b = grp * 8 + xc;
  const int m0 = (r % 9) * 128;
  const int n0 = (r / 9) * 64;
  const int tid = threadIdx.x, l = tid & 63, w = tid >> 6;
  const int wm = (w & 1) * 64, wn = (w >> 1) * 32;

  auto stage = [&](int kt, int buf) {
    #pragma unroll
    for (int s = 0; s < 2; ++s) {   // A: 8KB
      const int o = w * 2048 + s * 1024 + l * 16;
      const int row = o >> 6;
      const int c = ((o >> 4) & 3) ^ ((row >> 1) & 3);
      GLL16(wqkv + (size_t)(m0 + row) * CIN + kt * 32 + c * 8,
            (char*)As[buf] + w * 2048 + s * 1024);
    }
    {                               // B: 4KB
      const int o = w * 1024 + l * 16;
      const int row = o >> 6;
      const int c = ((o >> 4) & 3) ^ ((row >> 1) & 3);
      int nr = n0 + row; nr = nr > NPIX - 1 ? NPIX - 1 : nr;
      GLL16(xT + ((size_t)b * NPIX + nr) * CIN + kt * 32 + c * 8,
            (char*)Bs[buf] + w * 1024);
    }
  };

  const f32x4 vzero = {0.f, 0.f, 0.f, 0.f};
  f32x4 acc[4][2];
  #pragma unroll
  for (int mi = 0; mi < 4; ++mi)
    #pragma unroll
    for (int ni = 0; ni < 2; ++ni) acc[mi][ni] = vzero;

  stage(0, 0);
  for (int kt = 0; kt < 12; ++kt) {
    const int buf = kt & 1;
    __syncthreads();                 // drains vmcnt: buf ready; prev readers done
    if (kt < 11) stage(kt + 1, buf ^ 1);
    bf16x8 af[4], bfr[2];
    #pragma unroll
    for (int mi = 0; mi < 4; ++mi) {
      const int row = wm + mi * 16 + (l & 15);
      const int byte = row * 64 + (((l >> 4) ^ ((row >> 1) & 3)) << 4);
      af[mi] = *(const bf16x8*)((const char*)As[buf] + byte);
    }
    #pragma unroll
    for (int ni = 0; ni < 2; ++ni) {
      const int row = wn + ni * 16 + (l & 15);
      const int byte = row * 64 + (((l >> 4) ^ ((row >> 1) & 3)) << 4);
      bfr[ni] = *(const bf16x8*)((const char*)Bs[buf] + byte);
    }
    __builtin_amdgcn_s_setprio(1);
    #pragma unroll
    for (int mi = 0; mi < 4; ++mi)
      #pragma unroll
      for (int ni = 0; ni < 2; ++ni)
        acc[mi][ni] = __builtin_amdgcn_mfma_f32_16x16x32_bf16(af[mi], bfr[ni], acc[mi][ni], 0, 0, 0);
    __builtin_amdgcn_s_setprio(0);
  }

  #pragma unroll
  for (int mi = 0; mi < 4; ++mi) {
    const int mrow0 = m0 + wm + mi * 16 + ((l >> 4) << 2);
    #pragma unroll
    for (int ni = 0; ni < 2; ++ni) {
      const int n = n0 + wn + ni * 16 + (l & 15);
      if (n >= NPIX) continue;
      const float v0 = acc[mi][ni][0] + bqkv[mrow0 + 0];
      const float v1 = acc[mi][ni][1] + bqkv[mrow0 + 1];
      const float v2 = acc[mi][ni][2] + bqkv[mrow0 + 2];
      const float v3 = acc[mi][ni][3] + bqkv[mrow0 + 3];
      if (mrow0 < MID) {
        const int h = mrow0 >> 5, d = mrow0 & 31;
        ush4 pk; pk[0] = f2bf(v0); pk[1] = f2bf(v1); pk[2] = f2bf(v2); pk[3] = f2bf(v3);
        *(ush4*)(q_s + (((size_t)b * NHEADS + h) * NPIX + n) * HDIM + d) = pk;
      } else if (mrow0 < 2 * MID) {
        const int m2 = mrow0 - MID, h = m2 >> 5, d = m2 & 31;
        ush4 pk; pk[0] = f2bf(v0); pk[1] = f2bf(v1); pk[2] = f2bf(v2); pk[3] = f2bf(v3);
        *(ush4*)(k_s + (((size_t)b * NHEADS + h) * NPIX + n) * HDIM + d) = pk;
      } else {
        const int m2 = mrow0 - 2 * MID, h = m2 >> 5, d = m2 & 31;
        u16* p = vt + (((size_t)b * NHEADS + h) * HDIM + d) * NPIX + n;
        p[0] = f2bf(v0); p[NPIX] = f2bf(v1); p[2 * NPIX] = f2bf(v2); p[3 * NPIX] = f2bf(v3);
      }
    }
  }
}

// ---------------- flash attention: counted-vmcnt pipeline, peeled tail --------------
__global__ __launch_bounds__(256) void attn(
    const u16* __restrict__ q_s, const u16* __restrict__ k_s, const u16* __restrict__ vt,
    const float* __restrict__ biasT, u16* __restrict__ oTb)
{
  __shared__ u16 Ks[2][64 * 32];   // [kv][d], 64B rows, key=(row>>1)&3
  __shared__ u16 Vs[2][32 * 64];   // [d][kv], 128B rows, key=row&7
  __shared__ u16 Ps[4][16 * 64];   // per-wave P [q][kv], conflict-free swizzle
  // XCD swizzle: 2496 blocks = 8 xcd * 24 grp * 13 qt; same (b,h) -> same XCD
  const int id = blockIdx.x;
  const int xc = id & 7, s0i = id >> 3;
  const int grp = s0i / 13, qt = s0i - grp * 13;
  const int bh = grp * 8 + xc;
  const int h = bh % NHEADS, b = bh / NHEADS;
  const int tid = threadIdx.x, l = tid & 63, w = tid >> 6;
  const int g = l >> 4, qr = l & 15;
  const int qbase = qt * 64 + w * 16;
  const float* biasTh = biasT + h * NBIAS;

  int qrow = qbase + qr; qrow = qrow > NPIX - 1 ? NPIX - 1 : qrow;
  const bf16x8 qf = gload16b(q_s + ((size_t)bh * NPIX + qrow) * HDIM + g * 8);  // vmcnt+1

  const int yi = (qrow * 2341) >> 16;          // qrow / 28
  const int fbase = 1512 - qrow - 27 * yi;     // flipped-table base

  // P LDS addresses: chunk key + half swizzle -> conflict-free writes AND reads
  const int key = (qr & 7) ^ ((qr & 8) >> 1);
  const int hsw = qr >> 3;
  int addrW[4];
  #pragma unroll
  for (int nf = 0; nf < 4; ++nf)
    addrW[nf] = qr * 128 + ((((nf << 1) + (g >> 1)) ^ key) << 4) + (((g & 1) ^ hsw) << 3);
  int addrR0[2], addrR1[2];
  #pragma unroll
  for (int kk = 0; kk < 2; ++kk) {
    const int cb = qr * 128 + (((kk * 4 + g) ^ key) << 4);
    addrR0[kk] = cb + (hsw << 3);
    addrR1[kk] = cb + ((1 ^ hsw) << 3);
  }

  // stage source pointers (main tiles clamp-free; tile-12 sources pre-clamped)
  const int o = w * 1024 + l * 16;
  const int krow = o >> 6;
  const int kc = ((o >> 4) & 3) ^ ((krow >> 1) & 3);
  const u16* kptr = k_s + ((size_t)bh * NPIX + krow) * HDIM + kc * 8;
  const int vd = o >> 7;
  const int vc = ((o >> 4) & 7) ^ (vd & 7);
  const u16* vptr = vt + ((size_t)bh * HDIM + vd) * NPIX + vc * 8;
  int krow12 = 768 + krow; krow12 = krow12 > NPIX - 1 ? NPIX - 1 : krow12;
  const u16* kptr12 = k_s + ((size_t)bh * NPIX + krow12) * HDIM + kc * 8;
  int vcol12 = 768 + vc * 8; vcol12 = vcol12 > NPIX - 8 ? NPIX - 8 : vcol12;
  const u16* vptr12 = vt + ((size_t)bh * HDIM + vd) * NPIX + vcol12;

  char* PsW = (char*)Ps[w];
  const f32x4 vzero = {0.f, 0.f, 0.f, 0.f};
  f32x4 oacc[2]; oacc[0] = vzero; oacc[1] = vzero;
  float lsum = 0.f;

  GLL16(kptr, (char*)Ks[0] + w * 1024);   // stage(0): vmcnt = qf + 2
  GLL16(vptr, (char*)Vs[0] + w * 1024);

  for (int t = 0; t < 12; ++t) {
    const int kv0 = t * 64;
    f32x4 bfrag[4];
    #pragma unroll
    for (int nf = 0; nf < 4; ++nf) {       // 4 bias loads (rows i..i+3, same j)
      const int j4 = kv0 + nf * 16 + g * 4;
      const int yj = (j4 * 2341) >> 16;
      const int idx = fbase + j4 + 27 * yj;
      bfrag[nf] = gload16f(biasTh + idx);
    }
    asm volatile("s_waitcnt vmcnt(4)" ::: "memory");  // my stage(t) [+qf at t=0] done
    __builtin_amdgcn_s_barrier();                      // all waves' stage(t) done
    {
      char* kd = (char*)Ks[(t + 1) & 1] + w * 1024;
      char* vdst = (char*)Vs[(t + 1) & 1] + w * 1024;
      if (t < 11) {
        GLL16(kptr + (size_t)(t + 1) * 64 * HDIM, kd);
        GLL16(vptr + (t + 1) * 64, vdst);
      } else {
        GLL16(kptr12, kd);
        GLL16(vptr12, vdst);
      }
    }
    asm volatile("s_waitcnt vmcnt(2)" ::: "memory");  // bias done; stage(t+1) in flight
    __builtin_amdgcn_sched_barrier(0);

    const char* KsB = (const char*)Ks[t & 1];
    const char* VsB = (const char*)Vs[t & 1];
    f32x4 s[4];
    __builtin_amdgcn_s_setprio(1);
    #pragma unroll
    for (int nf = 0; nf < 4; ++nf) {
      const int row = nf * 16 + qr;
      const int byte = row * 64 + ((g ^ ((row >> 1) & 3)) << 4);
      const bf16x8 kf = *(const bf16x8*)(KsB + byte);
      s[nf] = __builtin_amdgcn_mfma_f32_16x16x32_bf16(kf, qf, bfrag[nf], 0, 0, 0);
    }
    __builtin_amdgcn_s_setprio(0);

    #pragma unroll
    for (int nf = 0; nf < 4; ++nf) {
      const float p0 = __builtin_amdgcn_exp2f(s[nf][0]);
      const float p1 = __builtin_amdgcn_exp2f(s[nf][1]);
      const float p2 = __builtin_amdgcn_exp2f(s[nf][2]);
      const float p3 = __builtin_amdgcn_exp2f(s[nf][3]);
      lsum += (p0 + p1) + (p2 + p3);
      u32x2 wpair;
      wpair[0] = cvtpk_bf16(p0, p1);
      wpair[1] = cvtpk_bf16(p2, p3);
      *(u32x2*)(PsW + addrW[nf]) = wpair;
    }

    __builtin_amdgcn_s_setprio(1);
    #pragma unroll
    for (int kk = 0; kk < 2; ++kk) {
      union { u32x2 u2[2]; bf16x8 v8; } pau;
      pau.u2[0] = *(const u32x2*)(PsW + addrR0[kk]);
      pau.u2[1] = *(const u32x2*)(PsW + addrR1[kk]);
      #pragma unroll
      for (int nf2 = 0; nf2 < 2; ++nf2) {
        const int d = nf2 * 16 + qr;
        const int vbyte = d * 128 + (((kk * 4 + g) ^ (d & 7)) << 4);
        const bf16x8 vb = *(const bf16x8*)(VsB + vbyte);
        oacc[nf2] = __builtin_amdgcn_mfma_f32_16x16x32_bf16(pau.v8, vb, oacc[nf2], 0, 0, 0);
      }
    }
    __builtin_amdgcn_s_setprio(0);
  }

  // ---- peeled tail t=12: kv 768..783 valid (exactly nf=0); buf 0 ----
  {
    const int j4 = 768 + g * 4;
    const int yj = (j4 * 2341) >> 16;
    const int idx = fbase + j4 + 27 * yj;
    const f32x4 bf0 = gload16f(biasTh + idx);
    asm volatile("s_waitcnt vmcnt(1)" ::: "memory");  // stage(12) done
    __builtin_amdgcn_s_barrier();
    asm volatile("s_waitcnt vmcnt(0)" ::: "memory");  // bias done
    __builtin_amdgcn_sched_barrier(0);

    const char* KsB = (const char*)Ks[0];
    const char* VsB = (const char*)Vs[0];
    const int byte = qr * 64 + ((g ^ ((qr >> 1) & 3)) << 4);
    const bf16x8 kf = *(const bf16x8*)(KsB + byte);
    const f32x4 s0 = __builtin_amdgcn_mfma_f32_16x16x32_bf16(kf, qf, bf0, 0, 0, 0);
    const float p0 = __builtin_amdgcn_exp2f(s0[0]);
    const float p1 = __builtin_amdgcn_exp2f(s0[1]);
    const float p2 = __builtin_amdgcn_exp2f(s0[2]);
    const float p3 = __builtin_amdgcn_exp2f(s0[3]);
    lsum += (p0 + p1) + (p2 + p3);
    u32x2 wpair;
    wpair[0] = cvtpk_bf16(p0, p1);
    wpair[1] = cvtpk_bf16(p2, p3);
    *(u32x2*)(PsW + addrW[0]) = wpair;
    const u32x2 zz = {0u, 0u};
    *(u32x2*)(PsW + addrW[1]) = zz;
    *(u32x2*)(PsW + addrW[2]) = zz;
    *(u32x2*)(PsW + addrW[3]) = zz;

    __builtin_amdgcn_s_setprio(1);
    #pragma unroll
    for (int kk = 0; kk < 2; ++kk) {
      union { u32x2 u2[2]; bf16x8 v8; } pau;
      pau.u2[0] = *(const u32x2*)(PsW + addrR0[kk]);
      pau.u2[1] = *(const u32x2*)(PsW + addrR1[kk]);
      #pragma unroll
      for (int nf2 = 0; nf2 < 2; ++nf2) {
        const int d = nf2 * 16 + qr;
        const int vbyte = d * 128 + (((kk * 4 + g) ^ (d & 7)) << 4);
        const bf16x8 vb = *(const bf16x8*)(VsB + vbyte);
        oacc[nf2] = __builtin_amdgcn_mfma_f32_16x16x32_bf16(pau.v8, vb, oacc[nf2], 0, 0, 0);
      }
    }
    __builtin_amdgcn_s_setprio(0);
  }

  // row-sum: combine the 4 kv-quarters
  lsum += __shfl_xor(lsum, 16, 64);
  lsum += __shfl_xor(lsum, 32, 64);

  #pragma unroll
  for (int jr = 0; jr < 4; ++jr) {
    const int i = qbase + g * 4 + jr;
    const float rsum = __shfl(lsum, g * 4 + jr, 64);
    if (i >= NPIX) continue;
    const float inv = 1.f / rsum;
    #pragma unroll
    for (int nf2 = 0; nf2 < 2; ++nf2) {
      const int m = h * HDIM + nf2 * 16 + qr;
      oTb[((size_t)b * NPIX + i) * MID + m] = f2bf(oacc[nf2][jr] * inv);
    }
  }
}

// ---------------- output proj: plain bf16 GEMM [384x384] @ oTb^T, dbuf --------------
__global__ __launch_bounds__(256) void proj_gemm(
    const u16* __restrict__ wp, const float* __restrict__ bp,
    const u16* __restrict__ oTb, float* __restrict__ out)
{
  __shared__ u16 Ah[2][128 * 32];
  __shared__ u16 Bh[2][64 * 32];
  // XCD swizzle: 624 blocks = 8 xcd * 2 grp * 39 (3 mt * 13 nt); same-b -> same XCD
  const int id = blockIdx.x;
  const int xc = id & 7, s0 = id >> 3;
  const int grp = s0 / 39, r = s0 - grp * 39;
  const int b = grp * 8 + xc;
  const int m0 = (r % 3) * 128;
  const int n0 = (r / 3) * 64;
  const int tid = threadIdx.x, l = tid & 63, w = tid >> 6;
  const int wm = (w & 1) * 64, wn = (w >> 1) * 32;

  auto stage = [&](int kt, int buf) {
    #pragma unroll
    for (int s = 0; s < 2; ++s) {
      const int o = w * 2048 + s * 1024 + l * 16;
      const int row = o >> 6;
      const int c = ((o >> 4) & 3) ^ ((row >> 1) & 3);
      GLL16(wp + (size_t)(m0 + row) * MID + kt * 32 + c * 8,
            (char*)Ah[buf] + w * 2048 + s * 1024);
    }
    {
      const int o = w * 1024 + l * 16;
      const int row = o >> 6;
      const int c = ((o >> 4) & 3) ^ ((row >> 1) & 3);
      int nr = n0 + row; nr = nr > NPIX - 1 ? NPIX - 1 : nr;
      GLL16(oTb + ((size_t)b * NPIX + nr) * MID + kt * 32 + c * 8,
            (char*)Bh[buf] + w * 1024);
    }
  };

  const f32x4 vzero = {0.f, 0.f, 0.f, 0.f};
  f32x4 acc[4][2];
  #pragma unroll
  for (int mi = 0; mi < 4; ++mi)
    #pragma unroll
    for (int ni = 0; ni < 2; ++ni) acc[mi][ni] = vzero;

  stage(0, 0);
  for (int kt = 0; kt < 12; ++kt) {
    const int buf = kt & 1;
    __syncthreads();
    if (kt < 11) stage(kt + 1, buf ^ 1);
    bf16x8 ah[4], bfr[2];
    #pragma unroll
    for (int mi = 0; mi < 4; ++mi) {
      const int row = wm + mi * 16 + (l & 15);
      const int byte = row * 64 + (((l >> 4) ^ ((row >> 1) & 3)) << 4);
      ah[mi] = *(const bf16x8*)((const char*)Ah[buf] + byte);
    }
    #pragma unroll
    for (int ni = 0; ni < 2; ++ni) {
      const int row = wn + ni * 16 + (l & 15);
      const int byte = row * 64 + (((l >> 4) ^ ((row >> 1) & 3)) << 4);
      bfr[ni] = *(const bf16x8*)((const char*)Bh[buf] + byte);
    }
    __builtin_amdgcn_s_setprio(1);
    #pragma unroll
    for (int mi = 0; mi < 4; ++mi)
      #pragma unroll
      for (int ni = 0; ni < 2; ++ni)
        acc[mi][ni] = __builtin_amdgcn_mfma_f32_16x16x32_bf16(ah[mi], bfr[ni], acc[mi][ni], 0, 0, 0);
    __builtin_amdgcn_s_setprio(0);
  }

  #pragma unroll
  for (int mi = 0; mi < 4; ++mi) {
    const int o0 = m0 + wm + mi * 16 + ((l >> 4) << 2);
    #pragma unroll
    for (int ni = 0; ni < 2; ++ni) {
      const int n = n0 + wn + ni * 16 + (l & 15);
      if (n >= NPIX) continue;
      #pragma unroll
      for (int jr = 0; jr < 4; ++jr)
        out[((size_t)b * MID + o0 + jr) * NPIX + n] = acc[mi][ni][jr] + bp[o0 + jr];
    }
  }
}

extern "C" void kernel_launch(void* const* d_in, const int* in_sizes, int n_in,
                              void* d_out, int out_size, void* d_ws, size_t ws_size,
                              hipStream_t stream) {
  const float* x          = (const float*)d_in[0];
  const float* Wq         = (const float*)d_in[1];
  const float* bq         = (const float*)d_in[2];
  const float* Wkv        = (const float*)d_in[3];
  const float* bkv        = (const float*)d_in[4];
  const float* bias_table = (const float*)d_in[5];
  const float* Wproj      = (const float*)d_in[6];
  const float* bproj      = (const float*)d_in[7];
  const float* gamma      = (const float*)d_in[8];

  char* ws = (char*)d_ws;
  u16*   xT    = (u16*)(ws + 0);          //  9,633,792 B
  u16*   wqkv  = (u16*)(ws + 9633792);    //    884,736 B
  u16*   wp    = (u16*)(ws + 10518528);   //    294,912 B
  float* bqkv  = (float*)(ws + 10813440); //      4,608 B
  float* bp    = (float*)(ws + 10818048); //      1,536 B
  float* biasT = (float*)(ws + 10819584); //    145,200 B (pad to 145,408)
  u16*   q_s   = (u16*)(ws + 10964992);   //  9,633,792 B
  u16*   k_s   = (u16*)(ws + 20598784);   //  9,633,792 B
  u16*   vt    = (u16*)(ws + 30232576);   //  9,633,792 B
  u16*   oTb   = (u16*)(ws + 39866368);   //  9,633,792 B  (total ~49.5 MB)
  float* out   = (float*)d_out;

  prep_all<<<dim3(2752), dim3(256), 0, stream>>>(x, Wq, bq, Wkv, bkv, Wproj, bproj, gamma,
                                                 bias_table, wqkv, wp, bqkv, bp, biasT, xT);
  qkv_gemm<<<dim3(1872), dim3(256), 0, stream>>>(wqkv, bqkv, xT, q_s, k_s, vt);
  attn<<<dim3(2496), dim3(256), 0, stream>>>(q_s, k_s, vt, biasT, oTb);
  proj_gemm<<<dim3(624), dim3(256), 0, stream>>>(wp, bp, oTb, out);
}